// Round 1
// baseline (1916.496 us; speedup 1.0000x reference)
//
#include <hip/hip_runtime.h>

// Problem constants (from reference)
#define N_NODES 100000
#define F_IN    128
#define H_DIM   128
#define Z_DIM   64
#define E_EDGES 1600000
#define EP_EDGES 200000

// ---------------- degree / normalization ----------------

__global__ __launch_bounds__(256) void deg_init_kernel(float* __restrict__ deg) {
    int i = blockIdx.x * 256 + threadIdx.x;
    if (i < N_NODES) deg[i] = 1.0f;   // self-loop contributes 1
}

__global__ __launch_bounds__(256) void deg_count_kernel(const int* __restrict__ dst,
                                                        float* __restrict__ deg) {
    int e = blockIdx.x * 256 + threadIdx.x;
    if (e < E_EDGES) atomicAdd(&deg[dst[e]], 1.0f);
}

__global__ __launch_bounds__(256) void deg_rsqrt_kernel(float* __restrict__ deg) {
    int i = blockIdx.x * 256 + threadIdx.x;
    if (i < N_NODES) deg[i] = rsqrtf(deg[i]);  // deg >= 1 always
}

// ---------------- simple fp32 GEMM, B staged in LDS ----------------
// C[M,NC] = op(A)[M,K] @ B[K,NC]; op = relu if RELU_A. One thread per output col,
// 16 rows per block. K*NC*4 bytes of LDS (64KB for 128x128, 32KB for 128x64).

template<int K, int NC, bool RELU_A>
__global__ __launch_bounds__(256) void gemm_smallB(const float* __restrict__ A,
                                                   const float* __restrict__ B,
                                                   float* __restrict__ C, int M) {
    __shared__ float Bs[K * NC];
    for (int i = threadIdx.x; i < K * NC; i += 256) Bs[i] = B[i];
    __syncthreads();

    const int ROWS  = 16;
    const int RSTEP = 256 / NC;
    int row0 = blockIdx.x * ROWS;
    int col  = threadIdx.x % NC;
    int rsub = threadIdx.x / NC;

    for (int r = row0 + rsub; r < row0 + ROWS && r < M; r += RSTEP) {
        const float4* a4 = (const float4*)(A + (size_t)r * K);
        float acc = 0.0f;
        #pragma unroll
        for (int k4 = 0; k4 < K / 4; ++k4) {
            float4 av = a4[k4];
            if (RELU_A) {
                av.x = fmaxf(av.x, 0.f); av.y = fmaxf(av.y, 0.f);
                av.z = fmaxf(av.z, 0.f); av.w = fmaxf(av.w, 0.f);
            }
            acc += av.x * Bs[(4 * k4 + 0) * NC + col];
            acc += av.y * Bs[(4 * k4 + 1) * NC + col];
            acc += av.z * Bs[(4 * k4 + 2) * NC + col];
            acc += av.w * Bs[(4 * k4 + 3) * NC + col];
        }
        C[(size_t)r * NC + col] = acc;
    }
}

// ---------------- aggregation ----------------
// out[n,f] = bias[f] + feat[n,f]*dinv[n]^2   (self-loop message fused into init)

template<int FD>
__global__ __launch_bounds__(256) void init_out_kernel(const float* __restrict__ feat,
                                                       const float* __restrict__ bias,
                                                       const float* __restrict__ dinv,
                                                       float* __restrict__ out) {
    long gid = (long)blockIdx.x * 256 + threadIdx.x;
    if (gid >= (long)N_NODES * FD) return;
    int n = (int)(gid / FD);
    int f = (int)(gid % FD);
    float di = dinv[n];
    out[gid] = bias[f] + feat[gid] * di * di;
}

// out[dst,f] += feat[src,f] * dinv[src]*dinv[dst]  over all E edges

template<int FD>
__global__ __launch_bounds__(256) void edge_scatter_kernel(const float* __restrict__ feat,
                                                           const int* __restrict__ srcs,
                                                           const int* __restrict__ dsts,
                                                           const float* __restrict__ dinv,
                                                           float* __restrict__ out) {
    long gid = (long)blockIdx.x * 256 + threadIdx.x;
    if (gid >= (long)E_EDGES * FD) return;
    int e = (int)(gid / FD);
    int f = (int)(gid % FD);
    int s = srcs[e];
    int d = dsts[e];
    float w = dinv[s] * dinv[d];
    atomicAdd(&out[(size_t)d * FD + f], feat[(size_t)s * FD + f] * w);
}

// ---------------- decoder: one wave per edge, dot-64 + shuffle reduce ----------------

__global__ __launch_bounds__(256) void decode_kernel(const float* __restrict__ latent,
                                                     const int* __restrict__ pos,
                                                     const int* __restrict__ neg,
                                                     float* __restrict__ out) {
    long gid = (long)blockIdx.x * 256 + threadIdx.x;
    int edge = (int)(gid >> 6);
    int lane = threadIdx.x & 63;
    if (edge >= 2 * EP_EDGES) return;
    int a, b;
    if (edge < EP_EDGES) {
        a = pos[edge];
        b = pos[EP_EDGES + edge];
    } else {
        int e2 = edge - EP_EDGES;
        a = neg[e2];
        b = neg[EP_EDGES + e2];
    }
    float v = latent[(size_t)a * Z_DIM + lane] * latent[(size_t)b * Z_DIM + lane];
    #pragma unroll
    for (int off = 32; off > 0; off >>= 1) v += __shfl_down(v, off, 64);
    if (lane == 0) out[edge] = v;
}

// ---------------- launcher ----------------

extern "C" void kernel_launch(void* const* d_in, const int* in_sizes, int n_in,
                              void* d_out, int out_size, void* d_ws, size_t ws_size,
                              hipStream_t stream) {
    const float* x  = (const float*)d_in[0];   // [N,128]
    const float* W1 = (const float*)d_in[1];   // [128,128]
    const float* b1 = (const float*)d_in[2];   // [128]
    const float* W2 = (const float*)d_in[3];   // [128,64]
    const float* b2 = (const float*)d_in[4];   // [64]
    const int* edge_index = (const int*)d_in[5]; // [2,E] flat
    const int* pos = (const int*)d_in[6];        // [2,EP] flat
    const int* neg = (const int*)d_in[7];        // [2,EP] flat
    float* out = (float*)d_out;                  // [2*EP]

    const int* src = edge_index;            // edge_index[0]
    const int* dst = edge_index + E_EDGES;  // edge_index[1]

    // workspace layout (fp32): dinv[N] | bufA[N*128] | bufB[N*128]  (~103 MB)
    float* dinv = (float*)d_ws;
    float* bufA = dinv + N_NODES;                 // byte off 400000 (16B aligned)
    float* bufB = bufA + (size_t)N_NODES * 128;

    // 1) degree -> dinv
    deg_init_kernel<<<(N_NODES + 255) / 256, 256, 0, stream>>>(dinv);
    deg_count_kernel<<<(E_EDGES + 255) / 256, 256, 0, stream>>>(dst, dinv);
    deg_rsqrt_kernel<<<(N_NODES + 255) / 256, 256, 0, stream>>>(dinv);

    // 2) h0 = x @ W1  -> bufA
    gemm_smallB<128, 128, false><<<(N_NODES + 15) / 16, 256, 0, stream>>>(x, W1, bufA, N_NODES);

    // 3) h = b1 + self + scatter(edges)  -> bufB
    {
        long total = (long)N_NODES * 128;
        init_out_kernel<128><<<(unsigned)((total + 255) / 256), 256, 0, stream>>>(bufA, b1, dinv, bufB);
        long etotal = (long)E_EDGES * 128;
        edge_scatter_kernel<128><<<(unsigned)((etotal + 255) / 256), 256, 0, stream>>>(bufA, src, dst, dinv, bufB);
    }

    // 4) h1 = relu(h) @ W2 -> bufA[0..N*64)
    gemm_smallB<128, 64, true><<<(N_NODES + 15) / 16, 256, 0, stream>>>(bufB, W2, bufA, N_NODES);

    // 5) latent = b2 + self + scatter(edges) -> bufB[0..N*64)
    {
        long total = (long)N_NODES * 64;
        init_out_kernel<64><<<(unsigned)((total + 255) / 256), 256, 0, stream>>>(bufA, b2, dinv, bufB);
        long etotal = (long)E_EDGES * 64;
        edge_scatter_kernel<64><<<(unsigned)((etotal + 255) / 256), 256, 0, stream>>>(bufA, src, dst, dinv, bufB);
    }

    // 6) decode: logits[i] = dot(latent[e0], latent[e1])
    {
        long total = (long)2 * EP_EDGES * 64;
        decode_kernel<<<(unsigned)((total + 255) / 256), 256, 0, stream>>>(bufB, pos, neg, out);
    }
}

// Round 2
// 1375.378 us; speedup vs baseline: 1.3934x; 1.3934x over previous
//
#include <hip/hip_runtime.h>

// Problem constants (from reference)
#define N_NODES 100000
#define F_IN    128
#define H_DIM   128
#define Z_DIM   64
#define E_EDGES 1600000
#define EP_EDGES 200000
#define NB_NODES ((N_NODES + 255) / 256)   // 391 blocks over nodes

// ---------------- degree count (int) ----------------

__global__ __launch_bounds__(256) void zero_cnt_kernel(int* __restrict__ cnt) {
    int i = blockIdx.x * 256 + threadIdx.x;
    if (i < N_NODES) cnt[i] = 0;
}

__global__ __launch_bounds__(256) void cnt_kernel(const int* __restrict__ dst,
                                                  int* __restrict__ cnt) {
    int e = blockIdx.x * 256 + threadIdx.x;
    if (e < E_EDGES) atomicAdd(&cnt[dst[e]], 1);
}

__global__ __launch_bounds__(256) void dinv_kernel(const int* __restrict__ cnt,
                                                   float* __restrict__ dinv) {
    int i = blockIdx.x * 256 + threadIdx.x;
    if (i < N_NODES) dinv[i] = rsqrtf(1.0f + (float)cnt[i]);  // +1 self-loop
}

// ---------------- exclusive scan over cnt (in place) ----------------
// scanA: per-block exclusive scan (in place), block sums out.
// scanB: single-block scan of block sums (exclusive, in place).
// scanC: add block offset in place -> cnt[] becomes global start offsets.

__global__ __launch_bounds__(256) void scanA_kernel(int* __restrict__ cnt,
                                                    int* __restrict__ bsum) {
    __shared__ int s[256];
    int t = threadIdx.x, i = blockIdx.x * 256 + t;
    int v = (i < N_NODES) ? cnt[i] : 0;
    s[t] = v;
    __syncthreads();
    #pragma unroll
    for (int off = 1; off < 256; off <<= 1) {
        int x = (t >= off) ? s[t - off] : 0;
        __syncthreads();
        s[t] += x;
        __syncthreads();
    }
    if (i < N_NODES) cnt[i] = s[t] - v;          // exclusive within block
    if (t == 255) bsum[blockIdx.x] = s[255];     // block total
}

__global__ __launch_bounds__(512) void scanB_kernel(int* __restrict__ bsum, int nb) {
    __shared__ int s[512];
    int t = threadIdx.x;
    int v = (t < nb) ? bsum[t] : 0;
    s[t] = v;
    __syncthreads();
    #pragma unroll
    for (int off = 1; off < 512; off <<= 1) {
        int x = (t >= off) ? s[t - off] : 0;
        __syncthreads();
        s[t] += x;
        __syncthreads();
    }
    if (t < nb) bsum[t] = s[t] - v;              // exclusive block offsets
}

__global__ __launch_bounds__(256) void scanC_kernel(int* __restrict__ cnt,
                                                    const int* __restrict__ bsum) {
    int i = blockIdx.x * 256 + threadIdx.x;
    if (i < N_NODES) cnt[i] += bsum[blockIdx.x]; // global start offset (== cursor)
}

// ---------------- CSR fill: cursor-based counting sort by dst ----------------
// csr[p] = { src, bits(w) } with w = dinv[src]*dinv[dst].
// After this kernel, cursor[n] == end offset of node n (== start of n+1).

__global__ __launch_bounds__(256) void fill_csr_kernel(const int* __restrict__ src,
                                                       const int* __restrict__ dst,
                                                       const float* __restrict__ dinv,
                                                       int* __restrict__ cursor,
                                                       int2* __restrict__ csr) {
    int e = blockIdx.x * 256 + threadIdx.x;
    if (e >= E_EDGES) return;
    int s = src[e], d = dst[e];
    int p = atomicAdd(&cursor[d], 1);
    int2 val;
    val.x = s;
    val.y = __float_as_int(dinv[s] * dinv[d]);
    csr[p] = val;
}

// ---------------- simple fp32 GEMM, B staged in LDS ----------------

template<int K, int NC, bool RELU_A>
__global__ __launch_bounds__(256) void gemm_smallB(const float* __restrict__ A,
                                                   const float* __restrict__ B,
                                                   float* __restrict__ C, int M) {
    __shared__ float Bs[K * NC];
    for (int i = threadIdx.x; i < K * NC; i += 256) Bs[i] = B[i];
    __syncthreads();

    const int ROWS  = 16;
    const int RSTEP = 256 / NC;
    int row0 = blockIdx.x * ROWS;
    int col  = threadIdx.x % NC;
    int rsub = threadIdx.x / NC;

    for (int r = row0 + rsub; r < row0 + ROWS && r < M; r += RSTEP) {
        const float4* a4 = (const float4*)(A + (size_t)r * K);
        float acc = 0.0f;
        #pragma unroll
        for (int k4 = 0; k4 < K / 4; ++k4) {
            float4 av = a4[k4];
            if (RELU_A) {
                av.x = fmaxf(av.x, 0.f); av.y = fmaxf(av.y, 0.f);
                av.z = fmaxf(av.z, 0.f); av.w = fmaxf(av.w, 0.f);
            }
            acc += av.x * Bs[(4 * k4 + 0) * NC + col];
            acc += av.y * Bs[(4 * k4 + 1) * NC + col];
            acc += av.z * Bs[(4 * k4 + 2) * NC + col];
            acc += av.w * Bs[(4 * k4 + 3) * NC + col];
        }
        C[(size_t)r * NC + col] = acc;
    }
}

// ---------------- node-parallel gather aggregation (no atomics) ----------------
// out[n,f] = bias[f] + feat[n,f]*dinv[n]^2 + sum_{j in CSR(n)} feat[csr[j].s, f]*csr[j].w
// ends[] is the post-fill cursor array: start(n) = n? ends[n-1] : 0; end(n) = ends[n].

template<int FD>
__global__ __launch_bounds__(256) void gather_kernel(const float* __restrict__ feat,
                                                     const float* __restrict__ bias,
                                                     const float* __restrict__ dinv,
                                                     const int* __restrict__ ends,
                                                     const int2* __restrict__ csr,
                                                     float* __restrict__ out) {
    const int NPB = 256 / FD;
    int n = blockIdx.x * NPB + threadIdx.x / FD;
    int f = threadIdx.x % FD;
    if (n >= N_NODES) return;
    float di = dinv[n];
    float acc = bias[f] + feat[(size_t)n * FD + f] * di * di;
    int j0 = (n > 0) ? ends[n - 1] : 0;
    int j1 = ends[n];
    for (int j = j0; j < j1; ++j) {
        int2 c = csr[j];
        acc += feat[(size_t)c.x * FD + f] * __int_as_float(c.y);
    }
    out[(size_t)n * FD + f] = acc;
}

// ---------------- decoder: one wave per edge, dot-64 + shuffle reduce ----------------

__global__ __launch_bounds__(256) void decode_kernel(const float* __restrict__ latent,
                                                     const int* __restrict__ pos,
                                                     const int* __restrict__ neg,
                                                     float* __restrict__ out) {
    long gid = (long)blockIdx.x * 256 + threadIdx.x;
    int edge = (int)(gid >> 6);
    int lane = threadIdx.x & 63;
    if (edge >= 2 * EP_EDGES) return;
    int a, b;
    if (edge < EP_EDGES) {
        a = pos[edge];
        b = pos[EP_EDGES + edge];
    } else {
        int e2 = edge - EP_EDGES;
        a = neg[e2];
        b = neg[EP_EDGES + e2];
    }
    float v = latent[(size_t)a * Z_DIM + lane] * latent[(size_t)b * Z_DIM + lane];
    #pragma unroll
    for (int off = 32; off > 0; off >>= 1) v += __shfl_down(v, off, 64);
    if (lane == 0) out[edge] = v;
}

// ---------------- launcher ----------------

extern "C" void kernel_launch(void* const* d_in, const int* in_sizes, int n_in,
                              void* d_out, int out_size, void* d_ws, size_t ws_size,
                              hipStream_t stream) {
    const float* x  = (const float*)d_in[0];     // [N,128]
    const float* W1 = (const float*)d_in[1];     // [128,128]
    const float* b1 = (const float*)d_in[2];     // [128]
    const float* W2 = (const float*)d_in[3];     // [128,64]
    const float* b2 = (const float*)d_in[4];     // [64]
    const int* edge_index = (const int*)d_in[5]; // [2,E] flat
    const int* pos = (const int*)d_in[6];        // [2,EP] flat
    const int* neg = (const int*)d_in[7];        // [2,EP] flat
    float* out = (float*)d_out;                  // [2*EP]

    const int* src = edge_index;                 // edge_index[0]
    const int* dst = edge_index + E_EDGES;       // edge_index[1]

    // workspace layout (all 4B elems; csr needs 8B alignment):
    //   dinv[N] | offs[N] (cnt -> excl -> cursor -> ends) | bsum[512] | csr[E]x8B | bufA[N*128] | bufB[N*128]
    float* dinv = (float*)d_ws;
    int*   offs = (int*)(dinv + N_NODES);
    int*   bsum = offs + N_NODES;
    int2*  csr  = (int2*)(bsum + 512);           // offset 300512*4 bytes, 8B-aligned
    float* bufA = (float*)(csr + E_EDGES);
    float* bufB = bufA + (size_t)N_NODES * 128;

    // 1) CSR build: count -> dinv -> scan -> fill
    zero_cnt_kernel<<<NB_NODES, 256, 0, stream>>>(offs);
    cnt_kernel<<<(E_EDGES + 255) / 256, 256, 0, stream>>>(dst, offs);
    dinv_kernel<<<NB_NODES, 256, 0, stream>>>(offs, dinv);
    scanA_kernel<<<NB_NODES, 256, 0, stream>>>(offs, bsum);
    scanB_kernel<<<1, 512, 0, stream>>>(bsum, NB_NODES);
    scanC_kernel<<<NB_NODES, 256, 0, stream>>>(offs, bsum);
    fill_csr_kernel<<<(E_EDGES + 255) / 256, 256, 0, stream>>>(src, dst, dinv, offs, csr);
    // offs[] now holds end offsets per node.

    // 2) h0 = x @ W1 -> bufA
    gemm_smallB<128, 128, false><<<(N_NODES + 15) / 16, 256, 0, stream>>>(x, W1, bufA, N_NODES);

    // 3) h = aggregate(h0) -> bufB  (bias + self + edges, fused)
    gather_kernel<128><<<(N_NODES + 1) / 2, 256, 0, stream>>>(bufA, b1, dinv, offs, csr, bufB);

    // 4) h1 = relu(h) @ W2 -> bufA[0 .. N*64)
    gemm_smallB<128, 64, true><<<(N_NODES + 15) / 16, 256, 0, stream>>>(bufB, W2, bufA, N_NODES);

    // 5) latent = aggregate(h1) -> bufA[N*64 .. N*128)
    float* latent = bufA + (size_t)N_NODES * 64;
    gather_kernel<64><<<(N_NODES + 3) / 4, 256, 0, stream>>>(bufA, b2, dinv, offs, csr, latent);

    // 6) decode: logits[i] = dot(latent[e0], latent[e1])
    {
        long total = (long)2 * EP_EDGES * 64;
        decode_kernel<<<(unsigned)((total + 255) / 256), 256, 0, stream>>>(latent, pos, neg, out);
    }
}

// Round 3
// 1069.059 us; speedup vs baseline: 1.7927x; 1.2865x over previous
//
#include <hip/hip_runtime.h>

// Problem constants (from reference)
#define N_NODES 100000
#define F_IN    128
#define H_DIM   128
#define Z_DIM   64
#define E_EDGES 1600000
#define EP_EDGES 200000
#define NB_NODES ((N_NODES + 255) / 256)   // 391 blocks over nodes

// ---------------- degree count (int) ----------------

__global__ __launch_bounds__(256) void zero_cnt_kernel(int* __restrict__ cnt) {
    int i = blockIdx.x * 256 + threadIdx.x;
    if (i < N_NODES) cnt[i] = 0;
}

__global__ __launch_bounds__(256) void cnt_kernel(const int* __restrict__ dst,
                                                  int* __restrict__ cnt) {
    int e = blockIdx.x * 256 + threadIdx.x;
    if (e < E_EDGES) atomicAdd(&cnt[dst[e]], 1);
}

__global__ __launch_bounds__(256) void dinv_kernel(const int* __restrict__ cnt,
                                                   float* __restrict__ dinv) {
    int i = blockIdx.x * 256 + threadIdx.x;
    if (i < N_NODES) dinv[i] = rsqrtf(1.0f + (float)cnt[i]);  // +1 self-loop
}

// ---------------- exclusive scan over cnt (in place) ----------------

__global__ __launch_bounds__(256) void scanA_kernel(int* __restrict__ cnt,
                                                    int* __restrict__ bsum) {
    __shared__ int s[256];
    int t = threadIdx.x, i = blockIdx.x * 256 + t;
    int v = (i < N_NODES) ? cnt[i] : 0;
    s[t] = v;
    __syncthreads();
    #pragma unroll
    for (int off = 1; off < 256; off <<= 1) {
        int x = (t >= off) ? s[t - off] : 0;
        __syncthreads();
        s[t] += x;
        __syncthreads();
    }
    if (i < N_NODES) cnt[i] = s[t] - v;          // exclusive within block
    if (t == 255) bsum[blockIdx.x] = s[255];     // block total
}

__global__ __launch_bounds__(512) void scanB_kernel(int* __restrict__ bsum, int nb) {
    __shared__ int s[512];
    int t = threadIdx.x;
    int v = (t < nb) ? bsum[t] : 0;
    s[t] = v;
    __syncthreads();
    #pragma unroll
    for (int off = 1; off < 512; off <<= 1) {
        int x = (t >= off) ? s[t - off] : 0;
        __syncthreads();
        s[t] += x;
        __syncthreads();
    }
    if (t < nb) bsum[t] = s[t] - v;              // exclusive block offsets
}

__global__ __launch_bounds__(256) void scanC_kernel(int* __restrict__ cnt,
                                                    const int* __restrict__ bsum) {
    int i = blockIdx.x * 256 + threadIdx.x;
    if (i < N_NODES) cnt[i] += bsum[blockIdx.x]; // global start offset (== cursor)
}

// ---------------- CSR fill: cursor-based counting sort by dst ----------------

__global__ __launch_bounds__(256) void fill_csr_kernel(const int* __restrict__ src,
                                                       const int* __restrict__ dst,
                                                       const float* __restrict__ dinv,
                                                       int* __restrict__ cursor,
                                                       int2* __restrict__ csr) {
    int e = blockIdx.x * 256 + threadIdx.x;
    if (e >= E_EDGES) return;
    int s = src[e], d = dst[e];
    int p = atomicAdd(&cursor[d], 1);
    int2 val;
    val.x = s;
    val.y = __float_as_int(dinv[s] * dinv[d]);
    csr[p] = val;
}

// ---------------- register-blocked fp32 GEMM ----------------
// C[M,NC] = op(A)[M,K] @ B[K,NC], op = relu if RELU_A.
// Thread (rgrp,col) computes RPT consecutive rows of one column; each Bs LDS
// read is reused across RPT accumulators; RPT A-loads issued back-to-back for
// ILP. K chunked at KC=64 so LDS stays at 32KB (NC=128) / 16KB (NC=64).
// M must be divisible by TM (100000 % 16 == 0, % 8 == 0).

template<int K, int NC, bool RELU_A>
__global__ __launch_bounds__(256, 4) void gemm_rb(const float* __restrict__ A,
                                                  const float* __restrict__ B,
                                                  float* __restrict__ C, int M) {
    const int KC  = 64;
    const int G   = 256 / NC;            // row groups per block
    const int RPT = (NC == 128) ? 8 : 4; // rows per thread
    const int TM  = G * RPT;             // rows per block
    __shared__ float Bs[KC * NC];        // 32KB or 16KB

    int col  = threadIdx.x % NC;
    int rgrp = threadIdx.x / NC;
    int row0 = blockIdx.x * TM + rgrp * RPT;

    float acc[RPT];
    #pragma unroll
    for (int r = 0; r < RPT; ++r) acc[r] = 0.0f;

    for (int kc = 0; kc < K; kc += KC) {
        // stage B chunk (contiguous rows kc..kc+KC of B), float4-wide
        {
            const float4* B4 = (const float4*)(B + (size_t)kc * NC);
            float4* Bs4 = (float4*)Bs;
            #pragma unroll
            for (int i = threadIdx.x; i < KC * NC / 4; i += 256) Bs4[i] = B4[i];
        }
        __syncthreads();

        #pragma unroll
        for (int k4 = 0; k4 < KC / 4; ++k4) {
            float4 av[RPT];
            #pragma unroll
            for (int r = 0; r < RPT; ++r) {
                av[r] = *(const float4*)(A + (size_t)(row0 + r) * K + kc + k4 * 4);
                if (RELU_A) {
                    av[r].x = fmaxf(av[r].x, 0.f); av[r].y = fmaxf(av[r].y, 0.f);
                    av[r].z = fmaxf(av[r].z, 0.f); av[r].w = fmaxf(av[r].w, 0.f);
                }
            }
            #pragma unroll
            for (int kk = 0; kk < 4; ++kk) {
                float b = Bs[(k4 * 4 + kk) * NC + col];
                #pragma unroll
                for (int r = 0; r < RPT; ++r)
                    acc[r] += (&av[r].x)[kk] * b;
            }
        }
        __syncthreads();
    }

    #pragma unroll
    for (int r = 0; r < RPT; ++r)
        C[(size_t)(row0 + r) * NC + col] = acc[r];
}

// ---------------- node-parallel gather aggregation (no atomics) ----------------
// out[n,f] = bias[f] + feat[n,f]*dinv[n]^2 + sum_{j in CSR(n)} feat[csr[j].s, f]*csr[j].w

template<int FD>
__global__ __launch_bounds__(256) void gather_kernel(const float* __restrict__ feat,
                                                     const float* __restrict__ bias,
                                                     const float* __restrict__ dinv,
                                                     const int* __restrict__ ends,
                                                     const int2* __restrict__ csr,
                                                     float* __restrict__ out) {
    const int NPB = 256 / FD;
    int n = blockIdx.x * NPB + threadIdx.x / FD;
    int f = threadIdx.x % FD;
    if (n >= N_NODES) return;
    float di = dinv[n];
    float acc = bias[f] + feat[(size_t)n * FD + f] * di * di;
    int j0 = (n > 0) ? ends[n - 1] : 0;
    int j1 = ends[n];
    for (int j = j0; j < j1; ++j) {
        int2 c = csr[j];
        acc += feat[(size_t)c.x * FD + f] * __int_as_float(c.y);
    }
    out[(size_t)n * FD + f] = acc;
}

// ---------------- decoder: one wave per edge, dot-64 + shuffle reduce ----------------

__global__ __launch_bounds__(256) void decode_kernel(const float* __restrict__ latent,
                                                     const int* __restrict__ pos,
                                                     const int* __restrict__ neg,
                                                     float* __restrict__ out) {
    long gid = (long)blockIdx.x * 256 + threadIdx.x;
    int edge = (int)(gid >> 6);
    int lane = threadIdx.x & 63;
    if (edge >= 2 * EP_EDGES) return;
    int a, b;
    if (edge < EP_EDGES) {
        a = pos[edge];
        b = pos[EP_EDGES + edge];
    } else {
        int e2 = edge - EP_EDGES;
        a = neg[e2];
        b = neg[EP_EDGES + e2];
    }
    float v = latent[(size_t)a * Z_DIM + lane] * latent[(size_t)b * Z_DIM + lane];
    #pragma unroll
    for (int off = 32; off > 0; off >>= 1) v += __shfl_down(v, off, 64);
    if (lane == 0) out[edge] = v;
}

// ---------------- launcher ----------------

extern "C" void kernel_launch(void* const* d_in, const int* in_sizes, int n_in,
                              void* d_out, int out_size, void* d_ws, size_t ws_size,
                              hipStream_t stream) {
    const float* x  = (const float*)d_in[0];     // [N,128]
    const float* W1 = (const float*)d_in[1];     // [128,128]
    const float* b1 = (const float*)d_in[2];     // [128]
    const float* W2 = (const float*)d_in[3];     // [128,64]
    const float* b2 = (const float*)d_in[4];     // [64]
    const int* edge_index = (const int*)d_in[5]; // [2,E] flat
    const int* pos = (const int*)d_in[6];        // [2,EP] flat
    const int* neg = (const int*)d_in[7];        // [2,EP] flat
    float* out = (float*)d_out;                  // [2*EP]

    const int* src = edge_index;                 // edge_index[0]
    const int* dst = edge_index + E_EDGES;       // edge_index[1]

    // workspace layout:
    //   dinv[N] | offs[N] | bsum[512] | csr[E]x8B | bufA[N*128] | bufB[N*128]
    float* dinv = (float*)d_ws;
    int*   offs = (int*)(dinv + N_NODES);
    int*   bsum = offs + N_NODES;
    int2*  csr  = (int2*)(bsum + 512);           // 8B-aligned
    float* bufA = (float*)(csr + E_EDGES);
    float* bufB = bufA + (size_t)N_NODES * 128;

    // 1) CSR build: count -> dinv -> scan -> fill
    zero_cnt_kernel<<<NB_NODES, 256, 0, stream>>>(offs);
    cnt_kernel<<<(E_EDGES + 255) / 256, 256, 0, stream>>>(dst, offs);
    dinv_kernel<<<NB_NODES, 256, 0, stream>>>(offs, dinv);
    scanA_kernel<<<NB_NODES, 256, 0, stream>>>(offs, bsum);
    scanB_kernel<<<1, 512, 0, stream>>>(bsum, NB_NODES);
    scanC_kernel<<<NB_NODES, 256, 0, stream>>>(offs, bsum);
    fill_csr_kernel<<<(E_EDGES + 255) / 256, 256, 0, stream>>>(src, dst, dinv, offs, csr);
    // offs[] now holds end offsets per node.

    // 2) h0 = x @ W1 -> bufA   (TM=16 rows/block -> 6250 blocks)
    gemm_rb<128, 128, false><<<N_NODES / 16, 256, 0, stream>>>(x, W1, bufA, N_NODES);

    // 3) h = aggregate(h0) -> bufB  (bias + self + edges, fused)
    gather_kernel<128><<<(N_NODES + 1) / 2, 256, 0, stream>>>(bufA, b1, dinv, offs, csr, bufB);

    // 4) h1 = relu(h) @ W2 -> bufA[0 .. N*64)  (TM=16 rows/block -> 6250 blocks)
    gemm_rb<128, 64, true><<<N_NODES / 16, 256, 0, stream>>>(bufB, W2, bufA, N_NODES);

    // 5) latent = aggregate(h1) -> bufA[N*64 .. N*128)
    float* latent = bufA + (size_t)N_NODES * 64;
    gather_kernel<64><<<(N_NODES + 3) / 4, 256, 0, stream>>>(bufA, b2, dinv, offs, csr, latent);

    // 6) decode: logits[i] = dot(latent[e0], latent[e1])
    {
        long total = (long)2 * EP_EDGES * 64;
        decode_kernel<<<(unsigned)((total + 255) / 256), 256, 0, stream>>>(latent, pos, neg, out);
    }
}

// Round 4
// 822.532 us; speedup vs baseline: 2.3300x; 1.2997x over previous
//
#include <hip/hip_runtime.h>

// Problem constants (from reference)
#define N_NODES 100000
#define F_IN    128
#define H_DIM   128
#define Z_DIM   64
#define E_EDGES 1600000
#define EP_EDGES 200000
#define NB_NODES ((N_NODES + 255) / 256)   // 391 blocks over nodes

// ---------------- degree count (int) ----------------

__global__ __launch_bounds__(256) void zero_cnt_kernel(int* __restrict__ cnt) {
    int i = blockIdx.x * 256 + threadIdx.x;
    if (i < N_NODES) cnt[i] = 0;
}

__global__ __launch_bounds__(256) void cnt_kernel(const int* __restrict__ dst,
                                                  int* __restrict__ cnt) {
    int e = blockIdx.x * 256 + threadIdx.x;
    if (e < E_EDGES) atomicAdd(&cnt[dst[e]], 1);
}

__global__ __launch_bounds__(256) void dinv_kernel(const int* __restrict__ cnt,
                                                   float* __restrict__ dinv) {
    int i = blockIdx.x * 256 + threadIdx.x;
    if (i < N_NODES) dinv[i] = rsqrtf(1.0f + (float)cnt[i]);  // +1 self-loop
}

// ---------------- exclusive scan over cnt (in place) ----------------

__global__ __launch_bounds__(256) void scanA_kernel(int* __restrict__ cnt,
                                                    int* __restrict__ bsum) {
    __shared__ int s[256];
    int t = threadIdx.x, i = blockIdx.x * 256 + t;
    int v = (i < N_NODES) ? cnt[i] : 0;
    s[t] = v;
    __syncthreads();
    #pragma unroll
    for (int off = 1; off < 256; off <<= 1) {
        int x = (t >= off) ? s[t - off] : 0;
        __syncthreads();
        s[t] += x;
        __syncthreads();
    }
    if (i < N_NODES) cnt[i] = s[t] - v;          // exclusive within block
    if (t == 255) bsum[blockIdx.x] = s[255];     // block total
}

__global__ __launch_bounds__(512) void scanB_kernel(int* __restrict__ bsum, int nb) {
    __shared__ int s[512];
    int t = threadIdx.x;
    int v = (t < nb) ? bsum[t] : 0;
    s[t] = v;
    __syncthreads();
    #pragma unroll
    for (int off = 1; off < 512; off <<= 1) {
        int x = (t >= off) ? s[t - off] : 0;
        __syncthreads();
        s[t] += x;
        __syncthreads();
    }
    if (t < nb) bsum[t] = s[t] - v;              // exclusive block offsets
}

__global__ __launch_bounds__(256) void scanC_kernel(int* __restrict__ cnt,
                                                    const int* __restrict__ bsum) {
    int i = blockIdx.x * 256 + threadIdx.x;
    if (i < N_NODES) cnt[i] += bsum[blockIdx.x]; // global start offset (== cursor)
}

// ---------------- CSR fill: cursor-based counting sort by dst ----------------

__global__ __launch_bounds__(256) void fill_csr_kernel(const int* __restrict__ src,
                                                       const int* __restrict__ dst,
                                                       const float* __restrict__ dinv,
                                                       int* __restrict__ cursor,
                                                       int2* __restrict__ csr) {
    int e = blockIdx.x * 256 + threadIdx.x;
    if (e >= E_EDGES) return;
    int s = src[e], d = dst[e];
    int p = atomicAdd(&cursor[d], 1);
    int2 val;
    val.x = s;
    val.y = __float_as_int(dinv[s] * dinv[d]);
    csr[p] = val;
}

// ---------------- register-blocked fp32 GEMM ----------------
// C[M,NC] = op(A)[M,K] @ B[K,NC], op = relu if RELU_A.

template<int K, int NC, bool RELU_A>
__global__ __launch_bounds__(256, 4) void gemm_rb(const float* __restrict__ A,
                                                  const float* __restrict__ B,
                                                  float* __restrict__ C, int M) {
    const int KC  = 64;
    const int G   = 256 / NC;            // row groups per block
    const int RPT = (NC == 128) ? 8 : 4; // rows per thread
    const int TM  = G * RPT;             // rows per block
    __shared__ float Bs[KC * NC];        // 32KB or 16KB

    int col  = threadIdx.x % NC;
    int rgrp = threadIdx.x / NC;
    int row0 = blockIdx.x * TM + rgrp * RPT;

    float acc[RPT];
    #pragma unroll
    for (int r = 0; r < RPT; ++r) acc[r] = 0.0f;

    for (int kc = 0; kc < K; kc += KC) {
        {
            const float4* B4 = (const float4*)(B + (size_t)kc * NC);
            float4* Bs4 = (float4*)Bs;
            #pragma unroll
            for (int i = threadIdx.x; i < KC * NC / 4; i += 256) Bs4[i] = B4[i];
        }
        __syncthreads();

        #pragma unroll
        for (int k4 = 0; k4 < KC / 4; ++k4) {
            float4 av[RPT];
            #pragma unroll
            for (int r = 0; r < RPT; ++r) {
                av[r] = *(const float4*)(A + (size_t)(row0 + r) * K + kc + k4 * 4);
                if (RELU_A) {
                    av[r].x = fmaxf(av[r].x, 0.f); av[r].y = fmaxf(av[r].y, 0.f);
                    av[r].z = fmaxf(av[r].z, 0.f); av[r].w = fmaxf(av[r].w, 0.f);
                }
            }
            #pragma unroll
            for (int kk = 0; kk < 4; ++kk) {
                float b = Bs[(k4 * 4 + kk) * NC + col];
                #pragma unroll
                for (int r = 0; r < RPT; ++r)
                    acc[r] += (&av[r].x)[kk] * b;
            }
        }
        __syncthreads();
    }

    #pragma unroll
    for (int r = 0; r < RPT; ++r)
        C[(size_t)(row0 + r) * NC + col] = acc[r];
}

// ---------------- node-parallel gather aggregation (no atomics) ----------------
// One wave per node; lane holds V=FD/64 contiguous floats. Edge loop unrolled
// x4 so 4 independent feat-row loads are in flight per wave (MLP).
// out[n,f] = bias[f] + feat[n,f]*dinv[n]^2 + sum_{j in CSR(n)} feat[csr[j].s,f]*w_j

template<int FD>
__global__ __launch_bounds__(256) void gather_kernel(const float* __restrict__ feat,
                                                     const float* __restrict__ bias,
                                                     const float* __restrict__ dinv,
                                                     const int* __restrict__ ends,
                                                     const int2* __restrict__ csr,
                                                     float* __restrict__ out) {
    constexpr int V = FD / 64;           // floats per lane (2 or 1)
    int wave = threadIdx.x >> 6;
    int lane = threadIdx.x & 63;
    int n = blockIdx.x * 4 + wave;
    if (n >= N_NODES) return;

    float di = dinv[n];
    float acc[V];
    #pragma unroll
    for (int v = 0; v < V; ++v)
        acc[v] = bias[lane * V + v] + feat[(size_t)n * FD + lane * V + v] * di * di;

    int j0 = (n > 0) ? ends[n - 1] : 0;
    int j1 = ends[n];
    int j = j0;
    for (; j + 3 < j1; j += 4) {
        int2 c0 = csr[j], c1 = csr[j + 1], c2 = csr[j + 2], c3 = csr[j + 3];
        const float* r0 = feat + (size_t)c0.x * FD + lane * V;
        const float* r1 = feat + (size_t)c1.x * FD + lane * V;
        const float* r2 = feat + (size_t)c2.x * FD + lane * V;
        const float* r3 = feat + (size_t)c3.x * FD + lane * V;
        float w0 = __int_as_float(c0.y), w1 = __int_as_float(c1.y);
        float w2 = __int_as_float(c2.y), w3 = __int_as_float(c3.y);
        float f0[V], f1[V], f2[V], f3[V];
        #pragma unroll
        for (int v = 0; v < V; ++v) f0[v] = r0[v];
        #pragma unroll
        for (int v = 0; v < V; ++v) f1[v] = r1[v];
        #pragma unroll
        for (int v = 0; v < V; ++v) f2[v] = r2[v];
        #pragma unroll
        for (int v = 0; v < V; ++v) f3[v] = r3[v];
        #pragma unroll
        for (int v = 0; v < V; ++v)
            acc[v] += f0[v] * w0 + f1[v] * w1 + f2[v] * w2 + f3[v] * w3;
    }
    for (; j < j1; ++j) {
        int2 c = csr[j];
        const float* r = feat + (size_t)c.x * FD + lane * V;
        float w = __int_as_float(c.y);
        #pragma unroll
        for (int v = 0; v < V; ++v) acc[v] += r[v] * w;
    }

    #pragma unroll
    for (int v = 0; v < V; ++v)
        out[(size_t)n * FD + lane * V + v] = acc[v];
}

// ---------------- decoder: 4 edges per wave, dot-64 + shuffle reduce ----------------
// 2*EP = 400000 edges = 100000 waves exactly (4 edges per wave).

__global__ __launch_bounds__(256) void decode_kernel(const float* __restrict__ latent,
                                                     const int* __restrict__ pos,
                                                     const int* __restrict__ neg,
                                                     float* __restrict__ out) {
    int gwave = (blockIdx.x * 256 + threadIdx.x) >> 6;
    int lane = threadIdx.x & 63;
    int e0 = gwave * 4;
    if (e0 >= 2 * EP_EDGES) return;

    int ia[4], ib[4];
    #pragma unroll
    for (int u = 0; u < 4; ++u) {
        int edge = e0 + u;
        if (edge < EP_EDGES) {
            ia[u] = pos[edge];
            ib[u] = pos[EP_EDGES + edge];
        } else {
            int e2 = edge - EP_EDGES;
            ia[u] = neg[e2];
            ib[u] = neg[EP_EDGES + e2];
        }
    }
    float v[4];
    #pragma unroll
    for (int u = 0; u < 4; ++u)
        v[u] = latent[(size_t)ia[u] * Z_DIM + lane] * latent[(size_t)ib[u] * Z_DIM + lane];
    #pragma unroll
    for (int u = 0; u < 4; ++u) {
        float s = v[u];
        #pragma unroll
        for (int off = 32; off > 0; off >>= 1) s += __shfl_down(s, off, 64);
        if (lane == 0) out[e0 + u] = s;
    }
}

// ---------------- launcher ----------------

extern "C" void kernel_launch(void* const* d_in, const int* in_sizes, int n_in,
                              void* d_out, int out_size, void* d_ws, size_t ws_size,
                              hipStream_t stream) {
    const float* x  = (const float*)d_in[0];     // [N,128]
    const float* W1 = (const float*)d_in[1];     // [128,128]
    const float* b1 = (const float*)d_in[2];     // [128]
    const float* W2 = (const float*)d_in[3];     // [128,64]
    const float* b2 = (const float*)d_in[4];     // [64]
    const int* edge_index = (const int*)d_in[5]; // [2,E] flat
    const int* pos = (const int*)d_in[6];        // [2,EP] flat
    const int* neg = (const int*)d_in[7];        // [2,EP] flat
    float* out = (float*)d_out;                  // [2*EP]

    const int* src = edge_index;                 // edge_index[0]
    const int* dst = edge_index + E_EDGES;       // edge_index[1]

    // workspace layout:
    //   dinv[N] | offs[N] | bsum[512] | csr[E]x8B | bufA[N*128] | bufB[N*128]
    float* dinv = (float*)d_ws;
    int*   offs = (int*)(dinv + N_NODES);
    int*   bsum = offs + N_NODES;
    int2*  csr  = (int2*)(bsum + 512);           // 8B-aligned
    float* bufA = (float*)(csr + E_EDGES);
    float* bufB = bufA + (size_t)N_NODES * 128;

    // 1) CSR build: count -> dinv -> scan -> fill
    zero_cnt_kernel<<<NB_NODES, 256, 0, stream>>>(offs);
    cnt_kernel<<<(E_EDGES + 255) / 256, 256, 0, stream>>>(dst, offs);
    dinv_kernel<<<NB_NODES, 256, 0, stream>>>(offs, dinv);
    scanA_kernel<<<NB_NODES, 256, 0, stream>>>(offs, bsum);
    scanB_kernel<<<1, 512, 0, stream>>>(bsum, NB_NODES);
    scanC_kernel<<<NB_NODES, 256, 0, stream>>>(offs, bsum);
    fill_csr_kernel<<<(E_EDGES + 255) / 256, 256, 0, stream>>>(src, dst, dinv, offs, csr);
    // offs[] now holds end offsets per node.

    // 2) h0 = x @ W1 -> bufA
    gemm_rb<128, 128, false><<<N_NODES / 16, 256, 0, stream>>>(x, W1, bufA, N_NODES);

    // 3) h = aggregate(h0) -> bufB  (bias + self + edges, fused); 4 nodes/block
    gather_kernel<128><<<N_NODES / 4, 256, 0, stream>>>(bufA, b1, dinv, offs, csr, bufB);

    // 4) h1 = relu(h) @ W2 -> bufA[0 .. N*64)
    gemm_rb<128, 64, true><<<N_NODES / 16, 256, 0, stream>>>(bufB, W2, bufA, N_NODES);

    // 5) latent = aggregate(h1) -> bufA[N*64 .. N*128)
    float* latent = bufA + (size_t)N_NODES * 64;
    gather_kernel<64><<<N_NODES / 4, 256, 0, stream>>>(bufA, b2, dinv, offs, csr, latent);

    // 6) decode: logits[i] = dot(latent[e0], latent[e1]); 16 edges/block
    decode_kernel<<<(2 * EP_EDGES) / 16, 256, 0, stream>>>(latent, pos, neg, out);
}

// Round 5
// 483.520 us; speedup vs baseline: 3.9636x; 1.7011x over previous
//
#include <hip/hip_runtime.h>

// Problem constants (from reference)
#define N_NODES 100000
#define F_IN    128
#define H_DIM   128
#define Z_DIM   64
#define E_EDGES 1600000
#define EP_EDGES 200000
#define NB_NODES ((N_NODES + 255) / 256)

typedef __attribute__((ext_vector_type(8))) short short8;   // 8 bf16 = 4 VGPRs
typedef __attribute__((ext_vector_type(4))) float f32x4;    // MFMA C/D frag
typedef unsigned int uint;
typedef unsigned short ushort;

// bf16 helpers (round-to-nearest-even, matches hardware cvt)
__device__ __forceinline__ ushort f2bf(float f) {
    uint u = __float_as_uint(f);
    u += 0x7fffu + ((u >> 16) & 1u);
    return (ushort)(u >> 16);
}
__device__ __forceinline__ float bflo(uint u) { return __uint_as_float(u << 16); }
__device__ __forceinline__ float bfhi(uint u) { return __uint_as_float(u & 0xffff0000u); }

// ---------------- degree count / dinv ----------------

__global__ __launch_bounds__(256) void zero_cnt_kernel(int* __restrict__ cnt) {
    int i = blockIdx.x * 256 + threadIdx.x;
    if (i < N_NODES) cnt[i] = 0;
}

__global__ __launch_bounds__(256) void cnt_kernel(const int* __restrict__ dst,
                                                  int* __restrict__ cnt) {
    int e = blockIdx.x * 256 + threadIdx.x;
    if (e < E_EDGES) atomicAdd(&cnt[dst[e]], 1);
}

__global__ __launch_bounds__(256) void dinv_kernel(const int* __restrict__ cnt,
                                                   float* __restrict__ dinv) {
    int i = blockIdx.x * 256 + threadIdx.x;
    if (i < N_NODES) dinv[i] = rsqrtf(1.0f + (float)cnt[i]);  // +1 self-loop
}

// ---------------- exclusive scan over cnt (in place) ----------------

__global__ __launch_bounds__(256) void scanA_kernel(int* __restrict__ cnt,
                                                    int* __restrict__ bsum) {
    __shared__ int s[256];
    int t = threadIdx.x, i = blockIdx.x * 256 + t;
    int v = (i < N_NODES) ? cnt[i] : 0;
    s[t] = v;
    __syncthreads();
    #pragma unroll
    for (int off = 1; off < 256; off <<= 1) {
        int x = (t >= off) ? s[t - off] : 0;
        __syncthreads();
        s[t] += x;
        __syncthreads();
    }
    if (i < N_NODES) cnt[i] = s[t] - v;
    if (t == 255) bsum[blockIdx.x] = s[255];
}

__global__ __launch_bounds__(512) void scanB_kernel(int* __restrict__ bsum, int nb) {
    __shared__ int s[512];
    int t = threadIdx.x;
    int v = (t < nb) ? bsum[t] : 0;
    s[t] = v;
    __syncthreads();
    #pragma unroll
    for (int off = 1; off < 512; off <<= 1) {
        int x = (t >= off) ? s[t - off] : 0;
        __syncthreads();
        s[t] += x;
        __syncthreads();
    }
    if (t < nb) bsum[t] = s[t] - v;
}

__global__ __launch_bounds__(256) void scanC_kernel(int* __restrict__ cnt,
                                                    const int* __restrict__ bsum) {
    int i = blockIdx.x * 256 + threadIdx.x;
    if (i < N_NODES) cnt[i] += bsum[blockIdx.x];
}

// ---------------- CSR fill: cursor-based counting sort by dst ----------------

__global__ __launch_bounds__(256) void fill_csr_kernel(const int* __restrict__ src,
                                                       const int* __restrict__ dst,
                                                       const float* __restrict__ dinv,
                                                       int* __restrict__ cursor,
                                                       int2* __restrict__ csr) {
    int e = blockIdx.x * 256 + threadIdx.x;
    if (e >= E_EDGES) return;
    int s = src[e], d = dst[e];
    int p = atomicAdd(&cursor[d], 1);
    int2 val;
    val.x = s;
    val.y = __float_as_int(dinv[s] * dinv[d]);
    csr[p] = val;
}

// ---------------- fp32 -> bf16 conversion (x) ----------------

__global__ __launch_bounds__(256) void cvt_bf16_kernel(const float* __restrict__ in,
                                                       ushort* __restrict__ out, int n4) {
    int i = blockIdx.x * 256 + threadIdx.x;
    if (i >= n4) return;
    float4 v = ((const float4*)in)[i];
    uint lo = (uint)f2bf(v.x) | ((uint)f2bf(v.y) << 16);
    uint hi = (uint)f2bf(v.z) | ((uint)f2bf(v.w) << 16);
    ((uint2*)out)[i] = make_uint2(lo, hi);
}

// ---------------- weight prep: transpose + cvt to bf16 ----------------
// W1T[n][k] = W1[k][n]  (128x128);  W2T[n][k] = W2[k][n]  (64x128)

__global__ __launch_bounds__(256) void wprep_kernel(const float* __restrict__ W1,
                                                    const float* __restrict__ W2,
                                                    ushort* __restrict__ W1T,
                                                    ushort* __restrict__ W2T) {
    int i = blockIdx.x * 256 + threadIdx.x;
    if (i < 128 * 128) {
        int n = i >> 7, k = i & 127;
        W1T[i] = f2bf(W1[k * 128 + n]);
    }
    int j = i - 128 * 128;
    if (j >= 0 && j < 64 * 128) {
        int n = j >> 7, k = j & 127;
        W2T[j] = f2bf(W2[k * 64 + n]);
    }
}

// ---------------- MFMA bf16 GEMM: C[M,NC] = A[M,128] @ B[128,NC] ----------------
// BT is B transposed [NC,128] bf16. B staged in LDS in fragment order
// [kc][nt][lane][j] -> each lane reads its own contiguous 16B (conflict-free).
// A-frag: lane reads A[row0+(lane&15)][kc*32+(lane>>4)*8 ..+7] = 16B global load.
// C/D layout (m89): col = lane&15, row = (lane>>4)*4 + reg.

template<int NC, bool OUT_BF16>
__global__ __launch_bounds__(256) void gemm_mfma_kernel(const ushort* __restrict__ A,
                                                        const ushort* __restrict__ BT,
                                                        void* __restrict__ C, int M) {
    constexpr int NT = NC / 16;
    __shared__ ushort Bs[4 * NT * 64 * 8];   // 32KB (NC=128) / 16KB (NC=64)

    for (int idx = threadIdx.x; idx < 4 * NT * 64; idx += 256) {
        int l   = idx & 63;
        int nt  = (idx >> 6) % NT;
        int kc  = idx / (64 * NT);
        int m16 = l & 15, quad = l >> 4;
        ((short8*)Bs)[idx] =
            *(const short8*)(BT + ((nt * 16 + m16) * 128 + kc * 32 + quad * 8));
    }
    __syncthreads();

    int wave = threadIdx.x >> 6, lane = threadIdx.x & 63;
    int m16 = lane & 15, quad = lane >> 4;
    int row0 = (blockIdx.x * 4 + wave) * 16;
    if (row0 >= M) return;
    int arow = row0 + m16;
    if (arow >= M) arow = M - 1;           // clamp loads; stores guarded

    f32x4 acc[NT];
    #pragma unroll
    for (int t = 0; t < NT; ++t) acc[t] = (f32x4){0.f, 0.f, 0.f, 0.f};

    #pragma unroll
    for (int kc = 0; kc < 4; ++kc) {
        short8 a = *(const short8*)(A + ((size_t)arow * 128 + kc * 32 + quad * 8));
        #pragma unroll
        for (int nt = 0; nt < NT; ++nt) {
            short8 b = ((const short8*)Bs)[(kc * NT + nt) * 64 + lane];
            acc[nt] = __builtin_amdgcn_mfma_f32_16x16x32_bf16(a, b, acc[nt], 0, 0, 0);
        }
    }

    #pragma unroll
    for (int nt = 0; nt < NT; ++nt) {
        #pragma unroll
        for (int r = 0; r < 4; ++r) {
            int row = row0 + quad * 4 + r;
            if (row < M) {
                size_t off = (size_t)row * NC + nt * 16 + m16;
                if (OUT_BF16) ((ushort*)C)[off] = f2bf(acc[nt][r]);
                else          ((float*)C)[off]  = acc[nt][r];
            }
        }
    }
}

// ---------------- gather FD=128, bf16 in/out, fused bias+self+ReLU ----------------
// One wave per node; lane holds 2 bf16 (one uint load). x4 unroll for MLP.

__global__ __launch_bounds__(256) void gather128_kernel(const ushort* __restrict__ feat,
                                                        const float* __restrict__ bias,
                                                        const float* __restrict__ dinv,
                                                        const int* __restrict__ ends,
                                                        const int2* __restrict__ csr,
                                                        ushort* __restrict__ out) {
    int wave = threadIdx.x >> 6, lane = threadIdx.x & 63;
    int n = blockIdx.x * 4 + wave;
    const uint* fu = (const uint*)feat;
    float di = dinv[n], wself = di * di;
    uint su = fu[(size_t)n * 64 + lane];
    float acc0 = bias[lane * 2]     + bflo(su) * wself;
    float acc1 = bias[lane * 2 + 1] + bfhi(su) * wself;
    int j0 = n ? ends[n - 1] : 0, j1 = ends[n];
    int j = j0;
    for (; j + 3 < j1; j += 4) {
        int2 c0 = csr[j], c1 = csr[j + 1], c2 = csr[j + 2], c3 = csr[j + 3];
        uint u0 = fu[(size_t)c0.x * 64 + lane];
        uint u1 = fu[(size_t)c1.x * 64 + lane];
        uint u2 = fu[(size_t)c2.x * 64 + lane];
        uint u3 = fu[(size_t)c3.x * 64 + lane];
        float w0 = __int_as_float(c0.y), w1 = __int_as_float(c1.y);
        float w2 = __int_as_float(c2.y), w3 = __int_as_float(c3.y);
        acc0 += bflo(u0) * w0 + bflo(u1) * w1 + bflo(u2) * w2 + bflo(u3) * w3;
        acc1 += bfhi(u0) * w0 + bfhi(u1) * w1 + bfhi(u2) * w2 + bfhi(u3) * w3;
    }
    for (; j < j1; ++j) {
        int2 c = csr[j];
        uint u = fu[(size_t)c.x * 64 + lane];
        float w = __int_as_float(c.y);
        acc0 += bflo(u) * w;
        acc1 += bfhi(u) * w;
    }
    acc0 = fmaxf(acc0, 0.f);
    acc1 = fmaxf(acc1, 0.f);
    ((uint*)out)[(size_t)n * 64 + lane] = (uint)f2bf(acc0) | ((uint)f2bf(acc1) << 16);
}

// ---------------- gather FD=64, fp32 in/out, fused bias+self ----------------

__global__ __launch_bounds__(256) void gather64_kernel(const float* __restrict__ feat,
                                                       const float* __restrict__ bias,
                                                       const float* __restrict__ dinv,
                                                       const int* __restrict__ ends,
                                                       const int2* __restrict__ csr,
                                                       float* __restrict__ out) {
    int wave = threadIdx.x >> 6, lane = threadIdx.x & 63;
    int n = blockIdx.x * 4 + wave;
    float di = dinv[n];
    float acc = bias[lane] + feat[(size_t)n * 64 + lane] * di * di;
    int j0 = n ? ends[n - 1] : 0, j1 = ends[n];
    int j = j0;
    for (; j + 3 < j1; j += 4) {
        int2 c0 = csr[j], c1 = csr[j + 1], c2 = csr[j + 2], c3 = csr[j + 3];
        float f0 = feat[(size_t)c0.x * 64 + lane];
        float f1 = feat[(size_t)c1.x * 64 + lane];
        float f2 = feat[(size_t)c2.x * 64 + lane];
        float f3 = feat[(size_t)c3.x * 64 + lane];
        acc += f0 * __int_as_float(c0.y) + f1 * __int_as_float(c1.y)
             + f2 * __int_as_float(c2.y) + f3 * __int_as_float(c3.y);
    }
    for (; j < j1; ++j) {
        int2 c = csr[j];
        acc += feat[(size_t)c.x * 64 + lane] * __int_as_float(c.y);
    }
    out[(size_t)n * 64 + lane] = acc;
}

// ---------------- decoder: 4 edges per wave ----------------

__global__ __launch_bounds__(256) void decode_kernel(const float* __restrict__ latent,
                                                     const int* __restrict__ pos,
                                                     const int* __restrict__ neg,
                                                     float* __restrict__ out) {
    int gwave = (blockIdx.x * 256 + threadIdx.x) >> 6;
    int lane = threadIdx.x & 63;
    int e0 = gwave * 4;
    if (e0 >= 2 * EP_EDGES) return;

    int ia[4], ib[4];
    #pragma unroll
    for (int u = 0; u < 4; ++u) {
        int edge = e0 + u;
        if (edge < EP_EDGES) {
            ia[u] = pos[edge];
            ib[u] = pos[EP_EDGES + edge];
        } else {
            int e2 = edge - EP_EDGES;
            ia[u] = neg[e2];
            ib[u] = neg[EP_EDGES + e2];
        }
    }
    float v[4];
    #pragma unroll
    for (int u = 0; u < 4; ++u)
        v[u] = latent[(size_t)ia[u] * Z_DIM + lane] * latent[(size_t)ib[u] * Z_DIM + lane];
    #pragma unroll
    for (int u = 0; u < 4; ++u) {
        float s = v[u];
        #pragma unroll
        for (int off = 32; off > 0; off >>= 1) s += __shfl_down(s, off, 64);
        if (lane == 0) out[e0 + u] = s;
    }
}

// ---------------- launcher ----------------

extern "C" void kernel_launch(void* const* d_in, const int* in_sizes, int n_in,
                              void* d_out, int out_size, void* d_ws, size_t ws_size,
                              hipStream_t stream) {
    const float* x  = (const float*)d_in[0];     // [N,128]
    const float* W1 = (const float*)d_in[1];     // [128,128]
    const float* b1 = (const float*)d_in[2];     // [128]
    const float* W2 = (const float*)d_in[3];     // [128,64]
    const float* b2 = (const float*)d_in[4];     // [64]
    const int* edge_index = (const int*)d_in[5]; // [2,E] flat
    const int* pos = (const int*)d_in[6];        // [2,EP] flat
    const int* neg = (const int*)d_in[7];        // [2,EP] flat
    float* out = (float*)d_out;                  // [2*EP]

    const int* src = edge_index;
    const int* dst = edge_index + E_EDGES;

    // ws layout: dinv[N] f32 | offs[N] i32 | bsum[512] | csr[E] int2 |
    //            W1T[16384] bf16 | W2T[8192] bf16 |
    //            bufX[N*128] bf16 (x_bf16 -> h_relu -> latent_f32) |
    //            bufH[N*128] bf16 (h0 -> l0_f32)          (~65 MB total)
    float*  dinv = (float*)d_ws;
    int*    offs = (int*)(dinv + N_NODES);
    int*    bsum = offs + N_NODES;
    int2*   csr  = (int2*)(bsum + 512);
    ushort* W1T  = (ushort*)(csr + E_EDGES);
    ushort* W2T  = W1T + 128 * 128;
    ushort* bufX = W2T + 64 * 128;
    ushort* bufH = bufX + (size_t)N_NODES * 128;

    // 1) CSR build
    zero_cnt_kernel<<<NB_NODES, 256, 0, stream>>>(offs);
    cnt_kernel<<<(E_EDGES + 255) / 256, 256, 0, stream>>>(dst, offs);
    dinv_kernel<<<NB_NODES, 256, 0, stream>>>(offs, dinv);
    scanA_kernel<<<NB_NODES, 256, 0, stream>>>(offs, bsum);
    scanB_kernel<<<1, 512, 0, stream>>>(bsum, NB_NODES);
    scanC_kernel<<<NB_NODES, 256, 0, stream>>>(offs, bsum);
    fill_csr_kernel<<<(E_EDGES + 255) / 256, 256, 0, stream>>>(src, dst, dinv, offs, csr);

    // 2) weight prep + x -> bf16
    wprep_kernel<<<96, 256, 0, stream>>>(W1, W2, W1T, W2T);
    cvt_bf16_kernel<<<(N_NODES * 128 / 4 + 255) / 256, 256, 0, stream>>>(x, bufX, N_NODES * 128 / 4);

    const int GEMM_GRID = (N_NODES + 63) / 64;   // 64 rows per block

    // 3) h0 = x @ W1 (MFMA) -> bufH bf16
    gemm_mfma_kernel<128, true><<<GEMM_GRID, 256, 0, stream>>>(bufX, W1T, bufH, N_NODES);

    // 4) h_relu = relu(b1 + Agg(h0)) -> bufX bf16
    gather128_kernel<<<N_NODES / 4, 256, 0, stream>>>(bufH, b1, dinv, offs, csr, bufX);

    // 5) l0 = h_relu @ W2 (MFMA) -> bufH fp32 [N,64]
    gemm_mfma_kernel<64, false><<<GEMM_GRID, 256, 0, stream>>>(bufX, W2T, bufH, N_NODES);

    // 6) latent = b2 + Agg(l0) -> bufX fp32 [N,64]
    float* l0     = (float*)bufH;
    float* latent = (float*)bufX;
    gather64_kernel<<<N_NODES / 4, 256, 0, stream>>>(l0, b2, dinv, offs, csr, latent);

    // 7) decode
    decode_kernel<<<(2 * EP_EDGES) / 16, 256, 0, stream>>>(latent, pos, neg, out);
}

// Round 6
// 424.939 us; speedup vs baseline: 4.5101x; 1.1379x over previous
//
#include <hip/hip_runtime.h>

// Problem constants (from reference)
#define N_NODES 100000
#define F_IN    128
#define H_DIM   128
#define Z_DIM   64
#define E_EDGES 1600000
#define EP_EDGES 200000
#define NB_NODES ((N_NODES + 255) / 256)

// bucket sort params: bucket = dst >> 7  (128 nodes/bucket)
#define BSHIFT 7
#define NBUCK  ((N_NODES + 127) >> 7)          // 782
#define CHUNK  8192
#define NCHUNK ((E_EDGES + CHUNK - 1) / CHUNK) // 196

typedef __attribute__((ext_vector_type(8))) short short8;   // 8 bf16 = 4 VGPRs
typedef __attribute__((ext_vector_type(4))) float f32x4;    // MFMA C/D frag
typedef unsigned int uint;
typedef unsigned short ushort;

// bf16 helpers (round-to-nearest-even)
__device__ __forceinline__ ushort f2bf(float f) {
    uint u = __float_as_uint(f);
    u += 0x7fffu + ((u >> 16) & 1u);
    return (ushort)(u >> 16);
}
__device__ __forceinline__ float bflo(uint u) { return __uint_as_float(u << 16); }
__device__ __forceinline__ float bfhi(uint u) { return __uint_as_float(u & 0xffff0000u); }
__device__ __forceinline__ float bf2f(ushort u) { return __uint_as_float((uint)u << 16); }

// ---------------- zero bucket cursors + node counts ----------------

__global__ __launch_bounds__(256) void zero_misc_kernel(int* __restrict__ gcur,
                                                        int* __restrict__ cnt) {
    int i = blockIdx.x * 256 + threadIdx.x;
    if (i < 1024) gcur[i] = 0;
    if (i < N_NODES) cnt[i] = 0;
}

// ---------------- bucket histogram (per-block LDS, then global) ----------------

__global__ __launch_bounds__(256) void bhist_kernel(const int* __restrict__ dst,
                                                    int* __restrict__ ghist) {
    __shared__ int lh[NBUCK];
    for (int i = threadIdx.x; i < NBUCK; i += 256) lh[i] = 0;
    __syncthreads();
    int base = blockIdx.x * CHUNK;
    int end = min(base + CHUNK, E_EDGES);
    for (int e = base + threadIdx.x; e < end; e += 256)
        atomicAdd(&lh[dst[e] >> BSHIFT], 1);
    __syncthreads();
    for (int i = threadIdx.x; i < NBUCK; i += 256)
        if (lh[i]) atomicAdd(&ghist[i], lh[i]);
}

// ---------------- exclusive scan over 782 bucket counts (single block) -------

__global__ __launch_bounds__(1024) void bscan_kernel(int* __restrict__ gc) {
    __shared__ int s[1024];
    int t = threadIdx.x;
    int v = (t < NBUCK) ? gc[t] : 0;
    s[t] = v;
    __syncthreads();
    #pragma unroll
    for (int off = 1; off < 1024; off <<= 1) {
        int x = (t >= off) ? s[t - off] : 0;
        __syncthreads();
        s[t] += x;
        __syncthreads();
    }
    if (t < NBUCK) gc[t] = s[t] - v;   // exclusive prefix -> running cursors
}

// ---------------- bucket scatter: edges -> bucket-grouped sorted[] ----------
// Per block: LDS hist of its chunk -> one global reservation per bucket ->
// second pass places each edge at lbase[b]++. Writes land in ~NBUCK dense runs
// within the block's private region -> L2 merges -> ~1x HBM write amp.

__global__ __launch_bounds__(256) void bscatter_kernel(const int* __restrict__ src,
                                                       const int* __restrict__ dst,
                                                       int* __restrict__ gcursor,
                                                       int2* __restrict__ sorted) {
    __shared__ int lh[NBUCK];
    __shared__ int lbase[NBUCK];
    for (int i = threadIdx.x; i < NBUCK; i += 256) lh[i] = 0;
    __syncthreads();
    int base = blockIdx.x * CHUNK;
    int end = min(base + CHUNK, E_EDGES);
    for (int e = base + threadIdx.x; e < end; e += 256)
        atomicAdd(&lh[dst[e] >> BSHIFT], 1);
    __syncthreads();
    for (int i = threadIdx.x; i < NBUCK; i += 256)
        lbase[i] = lh[i] ? atomicAdd(&gcursor[i], lh[i]) : 0;
    __syncthreads();
    for (int e = base + threadIdx.x; e < end; e += 256) {
        int d = dst[e];
        int p = atomicAdd(&lbase[d >> BSHIFT], 1);
        sorted[p] = make_int2(src[e], d);
    }
}

// ---------------- node degree count over sorted edges (L2-local atomics) ----

__global__ __launch_bounds__(256) void cnt_sorted_kernel(const int2* __restrict__ sorted,
                                                         int* __restrict__ cnt) {
    int e = blockIdx.x * 256 + threadIdx.x;
    if (e < E_EDGES) atomicAdd(&cnt[sorted[e].y], 1);
}

__global__ __launch_bounds__(256) void dinv_kernel(const int* __restrict__ cnt,
                                                   float* __restrict__ dinv) {
    int i = blockIdx.x * 256 + threadIdx.x;
    if (i < N_NODES) dinv[i] = rsqrtf(1.0f + (float)cnt[i]);  // +1 self-loop
}

// ---------------- exclusive scan over node counts (in place) ----------------

__global__ __launch_bounds__(256) void scanA_kernel(int* __restrict__ cnt,
                                                    int* __restrict__ bsum) {
    __shared__ int s[256];
    int t = threadIdx.x, i = blockIdx.x * 256 + t;
    int v = (i < N_NODES) ? cnt[i] : 0;
    s[t] = v;
    __syncthreads();
    #pragma unroll
    for (int off = 1; off < 256; off <<= 1) {
        int x = (t >= off) ? s[t - off] : 0;
        __syncthreads();
        s[t] += x;
        __syncthreads();
    }
    if (i < N_NODES) cnt[i] = s[t] - v;
    if (t == 255) bsum[blockIdx.x] = s[255];
}

__global__ __launch_bounds__(512) void scanB_kernel(int* __restrict__ bsum, int nb) {
    __shared__ int s[512];
    int t = threadIdx.x;
    int v = (t < nb) ? bsum[t] : 0;
    s[t] = v;
    __syncthreads();
    #pragma unroll
    for (int off = 1; off < 512; off <<= 1) {
        int x = (t >= off) ? s[t - off] : 0;
        __syncthreads();
        s[t] += x;
        __syncthreads();
    }
    if (t < nb) bsum[t] = s[t] - v;
}

__global__ __launch_bounds__(256) void scanC_kernel(int* __restrict__ cnt,
                                                    const int* __restrict__ bsum) {
    int i = blockIdx.x * 256 + threadIdx.x;
    if (i < N_NODES) cnt[i] += bsum[blockIdx.x];
}

// ---------------- final CSR fill from sorted edges (src only, 4B) ----------
// Blocks iterate bucket-grouped edges -> cursor atomics and csr writes stay in
// a ~8KB rolling window -> L2-merged, ~1x amp.

__global__ __launch_bounds__(256) void fill_csr_kernel(const int2* __restrict__ sorted,
                                                       int* __restrict__ cursor,
                                                       int* __restrict__ csr) {
    int e = blockIdx.x * 256 + threadIdx.x;
    if (e >= E_EDGES) return;
    int2 sd = sorted[e];
    int p = atomicAdd(&cursor[sd.y], 1);
    csr[p] = sd.x;
}

// ---------------- weight prep: transpose + cvt to bf16 ----------------

__global__ __launch_bounds__(256) void wprep_kernel(const float* __restrict__ W1,
                                                    const float* __restrict__ W2,
                                                    ushort* __restrict__ W1T,
                                                    ushort* __restrict__ W2T) {
    int i = blockIdx.x * 256 + threadIdx.x;
    if (i < 128 * 128) {
        int n = i >> 7, k = i & 127;
        W1T[i] = f2bf(W1[k * 128 + n]);
    }
    int j = i - 128 * 128;
    if (j >= 0 && j < 64 * 128) {
        int n = j >> 7, k = j & 127;
        W2T[j] = f2bf(W2[k * 64 + n]);
    }
}

// ---------------- MFMA bf16 GEMM with dinv-prescaled bf16 output ----------
// C[row] = (A[row] @ B) * dinv[row], bf16. A fp32 (converted in-register) or bf16.
// B staged in LDS in fragment order; A-frag is a direct 16B/32B global load.
// C/D layout: col = lane&15, row = (lane>>4)*4 + reg.

template<int NC, bool A_F32>
__global__ __launch_bounds__(256) void gemm_mfma_kernel(const void* __restrict__ Ap,
                                                        const ushort* __restrict__ BT,
                                                        const float* __restrict__ dinv,
                                                        ushort* __restrict__ C, int M) {
    constexpr int NT = NC / 16;
    __shared__ ushort Bs[4 * NT * 64 * 8];   // 32KB (NC=128) / 16KB (NC=64)

    for (int idx = threadIdx.x; idx < 4 * NT * 64; idx += 256) {
        int l   = idx & 63;
        int nt  = (idx >> 6) % NT;
        int kc  = idx / (64 * NT);
        int m16 = l & 15, quad = l >> 4;
        ((short8*)Bs)[idx] =
            *(const short8*)(BT + ((nt * 16 + m16) * 128 + kc * 32 + quad * 8));
    }
    __syncthreads();

    int wave = threadIdx.x >> 6, lane = threadIdx.x & 63;
    int m16 = lane & 15, quad = lane >> 4;
    int row0 = (blockIdx.x * 4 + wave) * 16;
    if (row0 >= M) return;
    int arow = row0 + m16;
    if (arow >= M) arow = M - 1;           // clamp loads; stores guarded

    f32x4 acc[NT];
    #pragma unroll
    for (int t = 0; t < NT; ++t) acc[t] = (f32x4){0.f, 0.f, 0.f, 0.f};

    #pragma unroll
    for (int kc = 0; kc < 4; ++kc) {
        short8 a;
        if (A_F32) {
            const float* A = (const float*)Ap;
            const float4* p = (const float4*)(A + (size_t)arow * 128 + kc * 32 + quad * 8);
            float4 x0 = p[0], x1 = p[1];
            a[0] = (short)f2bf(x0.x); a[1] = (short)f2bf(x0.y);
            a[2] = (short)f2bf(x0.z); a[3] = (short)f2bf(x0.w);
            a[4] = (short)f2bf(x1.x); a[5] = (short)f2bf(x1.y);
            a[6] = (short)f2bf(x1.z); a[7] = (short)f2bf(x1.w);
        } else {
            a = *(const short8*)((const ushort*)Ap + (size_t)arow * 128 + kc * 32 + quad * 8);
        }
        #pragma unroll
        for (int nt = 0; nt < NT; ++nt) {
            short8 b = ((const short8*)Bs)[(kc * NT + nt) * 64 + lane];
            acc[nt] = __builtin_amdgcn_mfma_f32_16x16x32_bf16(a, b, acc[nt], 0, 0, 0);
        }
    }

    #pragma unroll
    for (int r = 0; r < 4; ++r) {
        int row = row0 + quad * 4 + r;
        if (row < M) {
            float dr = dinv[row];
            #pragma unroll
            for (int nt = 0; nt < NT; ++nt)
                C[(size_t)row * NC + nt * 16 + m16] = f2bf(acc[nt][r] * dr);
        }
    }
}

// ---------------- gather FD=128: bf16 scaled rows, weightless CSR ----------
// out[n] = relu(bias + dinv[n] * (featS[n] + sum_j featS[csr[j]]))  (bf16 out)

__global__ __launch_bounds__(256) void gather128_kernel(const ushort* __restrict__ feat,
                                                        const float* __restrict__ bias,
                                                        const float* __restrict__ dinv,
                                                        const int* __restrict__ ends,
                                                        const int* __restrict__ csr,
                                                        ushort* __restrict__ out) {
    int wave = threadIdx.x >> 6, lane = threadIdx.x & 63;
    int n = blockIdx.x * 4 + wave;
    const uint* fu = (const uint*)feat;
    uint su = fu[(size_t)n * 64 + lane];
    float acc0 = bflo(su), acc1 = bfhi(su);
    int j0 = n ? ends[n - 1] : 0, j1 = ends[n];
    int j = j0;
    for (; j + 7 < j1; j += 8) {
        int s[8];
        #pragma unroll
        for (int u = 0; u < 8; ++u) s[u] = csr[j + u];
        uint f[8];
        #pragma unroll
        for (int u = 0; u < 8; ++u) f[u] = fu[(size_t)s[u] * 64 + lane];
        #pragma unroll
        for (int u = 0; u < 8; ++u) { acc0 += bflo(f[u]); acc1 += bfhi(f[u]); }
    }
    for (; j < j1; ++j) {
        uint f = fu[(size_t)csr[j] * 64 + lane];
        acc0 += bflo(f);
        acc1 += bfhi(f);
    }
    float dn = dinv[n];
    float r0 = fmaxf(bias[lane * 2]     + dn * acc0, 0.f);
    float r1 = fmaxf(bias[lane * 2 + 1] + dn * acc1, 0.f);
    ((uint*)out)[(size_t)n * 64 + lane] = (uint)f2bf(r0) | ((uint)f2bf(r1) << 16);
}

// ---------------- gather FD=64: bf16 scaled rows -> fp32 latent ----------

__global__ __launch_bounds__(256) void gather64_kernel(const ushort* __restrict__ feat,
                                                       const float* __restrict__ bias,
                                                       const float* __restrict__ dinv,
                                                       const int* __restrict__ ends,
                                                       const int* __restrict__ csr,
                                                       float* __restrict__ out) {
    int wave = threadIdx.x >> 6, lane = threadIdx.x & 63;
    int n = blockIdx.x * 4 + wave;
    float acc = bf2f(feat[(size_t)n * 64 + lane]);
    int j0 = n ? ends[n - 1] : 0, j1 = ends[n];
    int j = j0;
    for (; j + 7 < j1; j += 8) {
        int s[8];
        #pragma unroll
        for (int u = 0; u < 8; ++u) s[u] = csr[j + u];
        float f[8];
        #pragma unroll
        for (int u = 0; u < 8; ++u) f[u] = bf2f(feat[(size_t)s[u] * 64 + lane]);
        #pragma unroll
        for (int u = 0; u < 8; ++u) acc += f[u];
    }
    for (; j < j1; ++j) acc += bf2f(feat[(size_t)csr[j] * 64 + lane]);
    out[(size_t)n * 64 + lane] = bias[lane] + dinv[n] * acc;
}

// ---------------- decoder: 4 edges per wave ----------------

__global__ __launch_bounds__(256) void decode_kernel(const float* __restrict__ latent,
                                                     const int* __restrict__ pos,
                                                     const int* __restrict__ neg,
                                                     float* __restrict__ out) {
    int gwave = (blockIdx.x * 256 + threadIdx.x) >> 6;
    int lane = threadIdx.x & 63;
    int e0 = gwave * 4;
    if (e0 >= 2 * EP_EDGES) return;

    int ia[4], ib[4];
    #pragma unroll
    for (int u = 0; u < 4; ++u) {
        int edge = e0 + u;
        if (edge < EP_EDGES) {
            ia[u] = pos[edge];
            ib[u] = pos[EP_EDGES + edge];
        } else {
            int e2 = edge - EP_EDGES;
            ia[u] = neg[e2];
            ib[u] = neg[EP_EDGES + e2];
        }
    }
    float v[4];
    #pragma unroll
    for (int u = 0; u < 4; ++u)
        v[u] = latent[(size_t)ia[u] * Z_DIM + lane] * latent[(size_t)ib[u] * Z_DIM + lane];
    #pragma unroll
    for (int u = 0; u < 4; ++u) {
        float s = v[u];
        #pragma unroll
        for (int off = 32; off > 0; off >>= 1) s += __shfl_down(s, off, 64);
        if (lane == 0) out[e0 + u] = s;
    }
}

// ---------------- launcher ----------------

extern "C" void kernel_launch(void* const* d_in, const int* in_sizes, int n_in,
                              void* d_out, int out_size, void* d_ws, size_t ws_size,
                              hipStream_t stream) {
    const float* x  = (const float*)d_in[0];     // [N,128]
    const float* W1 = (const float*)d_in[1];     // [128,128]
    const float* b1 = (const float*)d_in[2];     // [128]
    const float* W2 = (const float*)d_in[3];     // [128,64]
    const float* b2 = (const float*)d_in[4];     // [64]
    const int* edge_index = (const int*)d_in[5]; // [2,E] flat
    const int* pos = (const int*)d_in[6];        // [2,EP] flat
    const int* neg = (const int*)d_in[7];        // [2,EP] flat
    float* out = (float*)d_out;                  // [2*EP]

    const int* src = edge_index;
    const int* dst = edge_index + E_EDGES;

    // ws: dinv[N] | offs[N] | bsum[512] | gcur[1024] | sorted[E] int2 |
    //     csr[E] int | W1T | W2T | bufH[N*128] bf16 | bufR[N*128] bf16
    float*  dinv   = (float*)d_ws;
    int*    offs   = (int*)(dinv + N_NODES);
    int*    bsum   = offs + N_NODES;
    int*    gcur   = bsum + 512;
    int2*   sorted = (int2*)(gcur + 1024);
    int*    csr    = (int*)(sorted + E_EDGES);
    ushort* W1T    = (ushort*)(csr + E_EDGES);
    ushort* W2T    = W1T + 128 * 128;
    ushort* bufH   = W2T + 64 * 128;
    ushort* bufR   = bufH + (size_t)N_NODES * 128;

    // 1) bucket sort edges by dst-block, then build CSR with local writes
    zero_misc_kernel<<<NB_NODES, 256, 0, stream>>>(gcur, offs);
    bhist_kernel<<<NCHUNK, 256, 0, stream>>>(dst, gcur);
    bscan_kernel<<<1, 1024, 0, stream>>>(gcur);
    bscatter_kernel<<<NCHUNK, 256, 0, stream>>>(src, dst, gcur, sorted);
    cnt_sorted_kernel<<<(E_EDGES + 255) / 256, 256, 0, stream>>>(sorted, offs);
    dinv_kernel<<<NB_NODES, 256, 0, stream>>>(offs, dinv);
    scanA_kernel<<<NB_NODES, 256, 0, stream>>>(offs, bsum);
    scanB_kernel<<<1, 512, 0, stream>>>(bsum, NB_NODES);
    scanC_kernel<<<NB_NODES, 256, 0, stream>>>(offs, bsum);
    fill_csr_kernel<<<(E_EDGES + 255) / 256, 256, 0, stream>>>(sorted, offs, csr);
    // offs[] now holds end offsets per node.

    // 2) weights -> bf16 transposed
    wprep_kernel<<<96, 256, 0, stream>>>(W1, W2, W1T, W2T);

    const int GEMM_GRID = (N_NODES + 63) / 64;

    // 3) h0_s = (x @ W1) * dinv  (fp32 A converted in-register) -> bufH bf16
    gemm_mfma_kernel<128, true><<<GEMM_GRID, 256, 0, stream>>>(x, W1T, dinv, bufH, N_NODES);

    // 4) h_relu = relu(b1 + dinv * (self + Agg)) -> bufR bf16
    gather128_kernel<<<N_NODES / 4, 256, 0, stream>>>(bufH, b1, dinv, offs, csr, bufR);

    // 5) l0_s = (h_relu @ W2) * dinv -> bufH bf16 [N,64]
    gemm_mfma_kernel<64, false><<<GEMM_GRID, 256, 0, stream>>>(bufR, W2T, dinv, bufH, N_NODES);

    // 6) latent = b2 + dinv * (self + Agg) -> bufR fp32 [N,64]
    float* latent = (float*)bufR;
    gather64_kernel<<<N_NODES / 4, 256, 0, stream>>>(bufH, b2, dinv, offs, csr, latent);

    // 7) decode
    decode_kernel<<<(2 * EP_EDGES) / 16, 256, 0, stream>>>(latent, pos, neg, out);
}

// Round 7
// 345.761 us; speedup vs baseline: 5.5428x; 1.2290x over previous
//
#include <hip/hip_runtime.h>

// Problem constants (from reference)
#define N_NODES 100000
#define F_IN    128
#define H_DIM   128
#define Z_DIM   64
#define E_EDGES 1600000
#define EP_EDGES 200000

// bucket sort params: bucket = dst >> 7  (128 nodes/bucket)
#define BSHIFT 7
#define NBUCK  ((N_NODES + 127) >> 7)          // 782
#define CHUNK  4096
#define NCHUNK ((E_EDGES + CHUNK - 1) / CHUNK) // 391

typedef __attribute__((ext_vector_type(8))) short short8;   // 8 bf16 = 4 VGPRs
typedef __attribute__((ext_vector_type(4))) float f32x4;    // MFMA C/D frag
typedef unsigned int uint;
typedef unsigned short ushort;

// bf16 helpers (round-to-nearest-even)
__device__ __forceinline__ ushort f2bf(float f) {
    uint u = __float_as_uint(f);
    u += 0x7fffu + ((u >> 16) & 1u);
    return (ushort)(u >> 16);
}
__device__ __forceinline__ float bflo(uint u) { return __uint_as_float(u << 16); }
__device__ __forceinline__ float bfhi(uint u) { return __uint_as_float(u & 0xffff0000u); }

// ---------------- zero bucket cursors ----------------

__global__ __launch_bounds__(256) void zero_gcur_kernel(int* __restrict__ gcur) {
    int i = blockIdx.x * 256 + threadIdx.x;
    if (i < 1024) gcur[i] = 0;
}

// ---------------- bucket histogram (per-block LDS, then global) ------------

__global__ __launch_bounds__(256) void bhist_kernel(const int* __restrict__ dst,
                                                    int* __restrict__ ghist) {
    __shared__ int lh[NBUCK];
    for (int i = threadIdx.x; i < NBUCK; i += 256) lh[i] = 0;
    __syncthreads();
    int base = blockIdx.x * CHUNK;
    int end = min(base + CHUNK, E_EDGES);
    for (int e = base + threadIdx.x; e < end; e += 256)
        atomicAdd(&lh[dst[e] >> BSHIFT], 1);
    __syncthreads();
    for (int i = threadIdx.x; i < NBUCK; i += 256)
        if (lh[i]) atomicAdd(&ghist[i], lh[i]);
}

// ---------------- exclusive scan over 782 bucket counts (single block) -----

__global__ __launch_bounds__(1024) void bscan_kernel(int* __restrict__ gc) {
    __shared__ int s[1024];
    int t = threadIdx.x;
    int v = (t < NBUCK) ? gc[t] : 0;
    s[t] = v;
    __syncthreads();
    #pragma unroll
    for (int off = 1; off < 1024; off <<= 1) {
        int x = (t >= off) ? s[t - off] : 0;
        __syncthreads();
        s[t] += x;
        __syncthreads();
    }
    if (t < NBUCK) gc[t] = s[t] - v;   // exclusive prefix -> running cursors
}

// ---------------- bucket scatter: edges -> bucket-grouped sorted[] ---------

__global__ __launch_bounds__(256) void bscatter_kernel(const int* __restrict__ src,
                                                       const int* __restrict__ dst,
                                                       int* __restrict__ gcursor,
                                                       int2* __restrict__ sorted) {
    __shared__ int lh[NBUCK];
    __shared__ int lbase[NBUCK];
    for (int i = threadIdx.x; i < NBUCK; i += 256) lh[i] = 0;
    __syncthreads();
    int base = blockIdx.x * CHUNK;
    int end = min(base + CHUNK, E_EDGES);
    for (int e = base + threadIdx.x; e < end; e += 256)
        atomicAdd(&lh[dst[e] >> BSHIFT], 1);
    __syncthreads();
    for (int i = threadIdx.x; i < NBUCK; i += 256)
        lbase[i] = lh[i] ? atomicAdd(&gcursor[i], lh[i]) : 0;
    __syncthreads();
    for (int e = base + threadIdx.x; e < end; e += 256) {
        int d = dst[e];
        int p = atomicAdd(&lbase[d >> BSHIFT], 1);
        sorted[p] = make_int2(src[e], d);
    }
    // after all blocks: gcursor[b] == end offset of bucket b
}

// ---------------- fused per-bucket CSR build ----------------
// One block per bucket (128 nodes). LDS histogram of node counts -> wave-0
// shfl scan -> ends[], dinv[], then node-grouped csr[] scatter. All writes
// land in the bucket's private region (L2-local).

__global__ __launch_bounds__(256) void bucket_csr_kernel(const int2* __restrict__ sorted,
                                                         const int* __restrict__ gcur,
                                                         int* __restrict__ csr,
                                                         int* __restrict__ ends,
                                                         float* __restrict__ dinv) {
    __shared__ int lcnt[128], lcur[128];
    int b = blockIdx.x, t = threadIdx.x;
    int bstart = b ? gcur[b - 1] : 0;
    int bend = gcur[b];
    if (t < 128) lcnt[t] = 0;
    __syncthreads();
    for (int i = bstart + t; i < bend; i += 256)
        atomicAdd(&lcnt[sorted[i].y & 127], 1);
    __syncthreads();
    if (t < 64) {                         // wave 0: scan 128 counts
        int c0 = lcnt[t], c1 = lcnt[t + 64];
        int s0 = c0;
        #pragma unroll
        for (int d = 1; d < 64; d <<= 1) {
            int x = __shfl_up(s0, d, 64);
            if (t >= d) s0 += x;
        }
        int tot0 = __shfl(s0, 63, 64);
        int s1 = c1;
        #pragma unroll
        for (int d = 1; d < 64; d <<= 1) {
            int x = __shfl_up(s1, d, 64);
            if (t >= d) s1 += x;
        }
        s1 += tot0;
        lcur[t] = s0 - c0;
        lcur[t + 64] = s1 - c1;
        int n0 = b * 128 + t, n1 = n0 + 64;
        if (n0 < N_NODES) { ends[n0] = bstart + s0; dinv[n0] = rsqrtf(1.0f + (float)c0); }
        if (n1 < N_NODES) { ends[n1] = bstart + s1; dinv[n1] = rsqrtf(1.0f + (float)c1); }
    }
    __syncthreads();
    for (int i = bstart + t; i < bend; i += 256) {
        int2 sd = sorted[i];
        int p = bstart + atomicAdd(&lcur[sd.y & 127], 1);
        csr[p] = sd.x;
    }
}

// ---------------- weight prep: transpose + cvt to bf16 ----------------

__global__ __launch_bounds__(256) void wprep_kernel(const float* __restrict__ W1,
                                                    const float* __restrict__ W2,
                                                    ushort* __restrict__ W1T,
                                                    ushort* __restrict__ W2T) {
    int i = blockIdx.x * 256 + threadIdx.x;
    if (i < 128 * 128) {
        int n = i >> 7, k = i & 127;
        W1T[i] = f2bf(W1[k * 128 + n]);
    }
    int j = i - 128 * 128;
    if (j >= 0 && j < 64 * 128) {
        int n = j >> 7, k = j & 127;
        W2T[j] = f2bf(W2[k * 64 + n]);
    }
}

// ---------------- MFMA bf16 GEMM with dinv-prescaled bf16 output ----------
// C[row] = (A[row] @ B) * dinv[row], bf16. A fp32 (converted in-register) or bf16.
// B staged in LDS in fragment order; A-frag is a direct 16B/32B global load.
// C/D layout: col = lane&15, row = (lane>>4)*4 + reg.

template<int NC, bool A_F32>
__global__ __launch_bounds__(256) void gemm_mfma_kernel(const void* __restrict__ Ap,
                                                        const ushort* __restrict__ BT,
                                                        const float* __restrict__ dinv,
                                                        ushort* __restrict__ C, int M) {
    constexpr int NT = NC / 16;
    __shared__ ushort Bs[4 * NT * 64 * 8];   // 32KB (NC=128) / 16KB (NC=64)

    for (int idx = threadIdx.x; idx < 4 * NT * 64; idx += 256) {
        int l   = idx & 63;
        int nt  = (idx >> 6) % NT;
        int kc  = idx / (64 * NT);
        int m16 = l & 15, quad = l >> 4;
        ((short8*)Bs)[idx] =
            *(const short8*)(BT + ((nt * 16 + m16) * 128 + kc * 32 + quad * 8));
    }
    __syncthreads();

    int wave = threadIdx.x >> 6, lane = threadIdx.x & 63;
    int m16 = lane & 15, quad = lane >> 4;
    int row0 = (blockIdx.x * 4 + wave) * 16;
    if (row0 >= M) return;
    int arow = row0 + m16;
    if (arow >= M) arow = M - 1;           // clamp loads; stores guarded

    f32x4 acc[NT];
    #pragma unroll
    for (int t = 0; t < NT; ++t) acc[t] = (f32x4){0.f, 0.f, 0.f, 0.f};

    #pragma unroll
    for (int kc = 0; kc < 4; ++kc) {
        short8 a;
        if (A_F32) {
            const float* A = (const float*)Ap;
            const float4* p = (const float4*)(A + (size_t)arow * 128 + kc * 32 + quad * 8);
            float4 x0 = p[0], x1 = p[1];
            a[0] = (short)f2bf(x0.x); a[1] = (short)f2bf(x0.y);
            a[2] = (short)f2bf(x0.z); a[3] = (short)f2bf(x0.w);
            a[4] = (short)f2bf(x1.x); a[5] = (short)f2bf(x1.y);
            a[6] = (short)f2bf(x1.z); a[7] = (short)f2bf(x1.w);
        } else {
            a = *(const short8*)((const ushort*)Ap + (size_t)arow * 128 + kc * 32 + quad * 8);
        }
        #pragma unroll
        for (int nt = 0; nt < NT; ++nt) {
            short8 b = ((const short8*)Bs)[(kc * NT + nt) * 64 + lane];
            acc[nt] = __builtin_amdgcn_mfma_f32_16x16x32_bf16(a, b, acc[nt], 0, 0, 0);
        }
    }

    #pragma unroll
    for (int r = 0; r < 4; ++r) {
        int row = row0 + quad * 4 + r;
        if (row < M) {
            float dr = dinv[row];
            #pragma unroll
            for (int nt = 0; nt < NT; ++nt)
                C[(size_t)row * NC + nt * 16 + m16] = f2bf(acc[nt][r] * dr);
        }
    }
}

// ---------------- gather FD=128: half-wave edge pairing ----------------
// Lanes 0-31 process even edges, 32-63 odd edges; uint2 (8B = 4 bf16) per lane.
// out[n] = relu(bias + dinv[n] * (featS[n] + sum_j featS[csr[j]]))  (bf16 out)

__global__ __launch_bounds__(256) void gather128_kernel(const ushort* __restrict__ feat,
                                                        const float* __restrict__ bias,
                                                        const float* __restrict__ dinv,
                                                        const int* __restrict__ ends,
                                                        const int* __restrict__ csr,
                                                        ushort* __restrict__ out) {
    int wave = threadIdx.x >> 6, lane = threadIdx.x & 63;
    int half = lane >> 5, sl = lane & 31;
    int n = blockIdx.x * 4 + wave;
    const uint2* fu = (const uint2*)feat;   // row = 32 x uint2 (256B)

    float a0 = 0.f, a1 = 0.f, a2 = 0.f, a3 = 0.f;
    if (half == 0) {                        // self row counted once
        uint2 s = fu[(size_t)n * 32 + sl];
        a0 = bflo(s.x); a1 = bfhi(s.x); a2 = bflo(s.y); a3 = bfhi(s.y);
    }
    int j0 = n ? ends[n - 1] : 0, j1 = ends[n];
    int j = j0 + half;
    for (; j + 6 < j1; j += 8) {            // 4 edges per half in flight
        int s0 = csr[j], s1 = csr[j + 2], s2 = csr[j + 4], s3 = csr[j + 6];
        uint2 f0 = fu[(size_t)s0 * 32 + sl];
        uint2 f1 = fu[(size_t)s1 * 32 + sl];
        uint2 f2 = fu[(size_t)s2 * 32 + sl];
        uint2 f3 = fu[(size_t)s3 * 32 + sl];
        a0 += bflo(f0.x) + bflo(f1.x) + bflo(f2.x) + bflo(f3.x);
        a1 += bfhi(f0.x) + bfhi(f1.x) + bfhi(f2.x) + bfhi(f3.x);
        a2 += bflo(f0.y) + bflo(f1.y) + bflo(f2.y) + bflo(f3.y);
        a3 += bfhi(f0.y) + bfhi(f1.y) + bfhi(f2.y) + bfhi(f3.y);
    }
    for (; j < j1; j += 2) {
        uint2 f = fu[(size_t)csr[j] * 32 + sl];
        a0 += bflo(f.x); a1 += bfhi(f.x); a2 += bflo(f.y); a3 += bfhi(f.y);
    }
    a0 += __shfl_xor(a0, 32, 64);
    a1 += __shfl_xor(a1, 32, 64);
    a2 += __shfl_xor(a2, 32, 64);
    a3 += __shfl_xor(a3, 32, 64);
    if (half == 0) {
        float dn = dinv[n];
        float r0 = fmaxf(bias[sl * 4 + 0] + dn * a0, 0.f);
        float r1 = fmaxf(bias[sl * 4 + 1] + dn * a1, 0.f);
        float r2 = fmaxf(bias[sl * 4 + 2] + dn * a2, 0.f);
        float r3 = fmaxf(bias[sl * 4 + 3] + dn * a3, 0.f);
        uint2 o;
        o.x = (uint)f2bf(r0) | ((uint)f2bf(r1) << 16);
        o.y = (uint)f2bf(r2) | ((uint)f2bf(r3) << 16);
        ((uint2*)out)[(size_t)n * 32 + sl] = o;
    }
}

// ---------------- gather FD=64: half-wave edge pairing, fp32 out ----------

__global__ __launch_bounds__(256) void gather64_kernel(const ushort* __restrict__ feat,
                                                       const float* __restrict__ bias,
                                                       const float* __restrict__ dinv,
                                                       const int* __restrict__ ends,
                                                       const int* __restrict__ csr,
                                                       float* __restrict__ out) {
    int wave = threadIdx.x >> 6, lane = threadIdx.x & 63;
    int half = lane >> 5, sl = lane & 31;
    int n = blockIdx.x * 4 + wave;
    const uint* fu = (const uint*)feat;     // row = 32 x uint (128B)

    float a0 = 0.f, a1 = 0.f;
    if (half == 0) {
        uint s = fu[(size_t)n * 32 + sl];
        a0 = bflo(s); a1 = bfhi(s);
    }
    int j0 = n ? ends[n - 1] : 0, j1 = ends[n];
    int j = j0 + half;
    for (; j + 6 < j1; j += 8) {
        int s0 = csr[j], s1 = csr[j + 2], s2 = csr[j + 4], s3 = csr[j + 6];
        uint f0 = fu[(size_t)s0 * 32 + sl];
        uint f1 = fu[(size_t)s1 * 32 + sl];
        uint f2 = fu[(size_t)s2 * 32 + sl];
        uint f3 = fu[(size_t)s3 * 32 + sl];
        a0 += bflo(f0) + bflo(f1) + bflo(f2) + bflo(f3);
        a1 += bfhi(f0) + bfhi(f1) + bfhi(f2) + bfhi(f3);
    }
    for (; j < j1; j += 2) {
        uint f = fu[(size_t)csr[j] * 32 + sl];
        a0 += bflo(f); a1 += bfhi(f);
    }
    a0 += __shfl_xor(a0, 32, 64);
    a1 += __shfl_xor(a1, 32, 64);
    if (half == 0) {
        float dn = dinv[n];
        float2 o;
        o.x = bias[sl * 2]     + dn * a0;
        o.y = bias[sl * 2 + 1] + dn * a1;
        ((float2*)out)[(size_t)n * 32 + sl] = o;
    }
}

// ---------------- decoder: 4 edges per wave ----------------

__global__ __launch_bounds__(256) void decode_kernel(const float* __restrict__ latent,
                                                     const int* __restrict__ pos,
                                                     const int* __restrict__ neg,
                                                     float* __restrict__ out) {
    int gwave = (blockIdx.x * 256 + threadIdx.x) >> 6;
    int lane = threadIdx.x & 63;
    int e0 = gwave * 4;
    if (e0 >= 2 * EP_EDGES) return;

    int ia[4], ib[4];
    #pragma unroll
    for (int u = 0; u < 4; ++u) {
        int edge = e0 + u;
        if (edge < EP_EDGES) {
            ia[u] = pos[edge];
            ib[u] = pos[EP_EDGES + edge];
        } else {
            int e2 = edge - EP_EDGES;
            ia[u] = neg[e2];
            ib[u] = neg[EP_EDGES + e2];
        }
    }
    float v[4];
    #pragma unroll
    for (int u = 0; u < 4; ++u)
        v[u] = latent[(size_t)ia[u] * Z_DIM + lane] * latent[(size_t)ib[u] * Z_DIM + lane];
    #pragma unroll
    for (int u = 0; u < 4; ++u) {
        float s = v[u];
        #pragma unroll
        for (int off = 32; off > 0; off >>= 1) s += __shfl_down(s, off, 64);
        if (lane == 0) out[e0 + u] = s;
    }
}

// ---------------- launcher ----------------

extern "C" void kernel_launch(void* const* d_in, const int* in_sizes, int n_in,
                              void* d_out, int out_size, void* d_ws, size_t ws_size,
                              hipStream_t stream) {
    const float* x  = (const float*)d_in[0];     // [N,128]
    const float* W1 = (const float*)d_in[1];     // [128,128]
    const float* b1 = (const float*)d_in[2];     // [128]
    const float* W2 = (const float*)d_in[3];     // [128,64]
    const float* b2 = (const float*)d_in[4];     // [64]
    const int* edge_index = (const int*)d_in[5]; // [2,E] flat
    const int* pos = (const int*)d_in[6];        // [2,EP] flat
    const int* neg = (const int*)d_in[7];        // [2,EP] flat
    float* out = (float*)d_out;                  // [2*EP]

    const int* src = edge_index;
    const int* dst = edge_index + E_EDGES;

    // ws: dinv[N] | ends[N] | gcur[1024] | sorted[E] int2 | csr[E] int |
    //     W1T | W2T | bufH[N*128] bf16 | bufR[N*128] bf16
    float*  dinv   = (float*)d_ws;
    int*    ends   = (int*)(dinv + N_NODES);
    int*    gcur   = ends + N_NODES;
    int2*   sorted = (int2*)(gcur + 1024);
    int*    csr    = (int*)(sorted + E_EDGES);
    ushort* W1T    = (ushort*)(csr + E_EDGES);
    ushort* W2T    = W1T + 128 * 128;
    ushort* bufH   = W2T + 64 * 128;
    ushort* bufR   = bufH + (size_t)N_NODES * 128;

    // 1) bucket sort edges by dst-block, then fused per-bucket CSR build
    zero_gcur_kernel<<<4, 256, 0, stream>>>(gcur);
    bhist_kernel<<<NCHUNK, 256, 0, stream>>>(dst, gcur);
    bscan_kernel<<<1, 1024, 0, stream>>>(gcur);
    bscatter_kernel<<<NCHUNK, 256, 0, stream>>>(src, dst, gcur, sorted);
    bucket_csr_kernel<<<NBUCK, 256, 0, stream>>>(sorted, gcur, csr, ends, dinv);

    // 2) weights -> bf16 transposed
    wprep_kernel<<<96, 256, 0, stream>>>(W1, W2, W1T, W2T);

    const int GEMM_GRID = (N_NODES + 63) / 64;

    // 3) h0_s = (x @ W1) * dinv  (fp32 A converted in-register) -> bufH bf16
    gemm_mfma_kernel<128, true><<<GEMM_GRID, 256, 0, stream>>>(x, W1T, dinv, bufH, N_NODES);

    // 4) h_relu = relu(b1 + dinv * (self + Agg)) -> bufR bf16
    gather128_kernel<<<N_NODES / 4, 256, 0, stream>>>(bufH, b1, dinv, ends, csr, bufR);

    // 5) l0_s = (h_relu @ W2) * dinv -> bufH bf16 [N,64]
    gemm_mfma_kernel<64, false><<<GEMM_GRID, 256, 0, stream>>>(bufR, W2T, dinv, bufH, N_NODES);

    // 6) latent = b2 + dinv * (self + Agg) -> bufR fp32 [N,64]
    float* latent = (float*)bufR;
    gather64_kernel<<<N_NODES / 4, 256, 0, stream>>>(bufH, b2, dinv, ends, csr, latent);

    // 7) decode
    decode_kernel<<<(2 * EP_EDGES) / 16, 256, 0, stream>>>(latent, pos, neg, out);
}